// Round 1
// baseline (250.546 us; speedup 1.0000x reference)
//
#include <hip/hip_runtime.h>
#include <hip/hip_bf16.h>

#define B_ 8
#define C_ 512
#define N_ 1024
#define HEADS_ 8
#define HD_ 64

using f32x4  = __attribute__((ext_vector_type(4))) float;
using bf16x8 = __attribute__((ext_vector_type(8))) __bf16;

__device__ __forceinline__ unsigned short f2bf(float f) {
  union { float f; unsigned u; } v; v.f = f;
  unsigned r = v.u + 0x7FFFu + ((v.u >> 16) & 1u);
  return (unsigned short)(r >> 16);
}

__device__ __forceinline__ void gload16(const void* g, void* l) {
  __builtin_amdgcn_global_load_lds(
      (const __attribute__((address_space(1))) unsigned int*)g,
      (__attribute__((address_space(3))) unsigned int*)l, 16, 0, 0);
}

// ---------------- weight f32->bf16 ----------------
__global__ __launch_bounds__(256) void k_convw(
    const float* __restrict__ wq, const float* __restrict__ wk,
    const float* __restrict__ wv, const float* __restrict__ wp,
    unsigned short* __restrict__ out) {
  int i = blockIdx.x * 256 + threadIdx.x;      // 0 .. 4*262144-1
  int mat = i >> 18, idx = i & 262143;
  const float* src = (mat == 0) ? wq : (mat == 1) ? wk : (mat == 2) ? wv : wp;
  out[i] = f2bf(src[idx]);
}

// ---------------- x [b][c][n] f32 -> xT [b][n][c] bf16 ----------------
__global__ __launch_bounds__(256) void k_transpose_x(
    const float* __restrict__ x, unsigned short* __restrict__ xT) {
  __shared__ float tile[64][65];
  int n0 = blockIdx.x * 64, c0 = blockIdx.y * 64, b = blockIdx.z;
  int t = threadIdx.x, tr = t >> 2, tc = (t & 3) * 16;
  const float* src = x + ((size_t)b * C_ + c0) * N_ + n0;
#pragma unroll
  for (int i = 0; i < 4; i++) {
    float4 v4 = *(const float4*)(src + (size_t)tr * N_ + tc + i * 4);
    tile[tr][tc + i * 4 + 0] = v4.x; tile[tr][tc + i * 4 + 1] = v4.y;
    tile[tr][tc + i * 4 + 2] = v4.z; tile[tr][tc + i * 4 + 3] = v4.w;
  }
  __syncthreads();
  unsigned short* dst = xT + ((size_t)b * N_ + n0) * C_ + c0;
#pragma unroll
  for (int i = 0; i < 4; i++) {
    unsigned short o4[4];
#pragma unroll
    for (int j = 0; j < 4; j++) o4[j] = f2bf(tile[tc + i * 4 + j][tr]);
    unsigned lo = (unsigned)o4[0] | ((unsigned)o4[1] << 16);
    unsigned hi = (unsigned)o4[2] | ((unsigned)o4[3] << 16);
    uint2 u; u.x = lo; u.y = hi;
    *(uint2*)(dst + (size_t)tr * C_ + tc + i * 4) = u;
  }
}

// ---------------- vT [b][n][c] bf16 -> vtr [b][c][n] bf16 ----------------
__global__ __launch_bounds__(256) void k_transpose_v(
    const unsigned short* __restrict__ vT, unsigned short* __restrict__ vtr) {
  __shared__ unsigned short tile[64][72];
  int n0 = blockIdx.x * 64, c0 = blockIdx.y * 64, b = blockIdx.z;
  int t = threadIdx.x, tr = t >> 2, tc = (t & 3) * 16;
  const unsigned short* src = vT + ((size_t)b * N_ + n0) * C_ + c0;
#pragma unroll
  for (int i = 0; i < 4; i++) {
    ushort4 v4 = *(const ushort4*)(src + (size_t)tr * C_ + tc + i * 4);
    tile[tr][tc + i * 4 + 0] = v4.x; tile[tr][tc + i * 4 + 1] = v4.y;
    tile[tr][tc + i * 4 + 2] = v4.z; tile[tr][tc + i * 4 + 3] = v4.w;
  }
  __syncthreads();
  unsigned short* dst = vtr + ((size_t)b * C_ + c0) * N_ + n0;
#pragma unroll
  for (int i = 0; i < 4; i++) {
    unsigned short o4[4];
#pragma unroll
    for (int j = 0; j < 4; j++) o4[j] = tile[tc + i * 4 + j][tr];
    unsigned lo = (unsigned)o4[0] | ((unsigned)o4[1] << 16);
    unsigned hi = (unsigned)o4[2] | ((unsigned)o4[3] << 16);
    uint2 u; u.x = lo; u.y = hi;
    *(uint2*)(dst + (size_t)tr * N_ + tc + i * 4) = u;
  }
}

// ---------------- gumbel argmax masks (f32 exactly) ----------------
__global__ __launch_bounds__(256) void k_mask(
    const float* __restrict__ x, const float* __restrict__ u_q, const float* __restrict__ u_k,
    const float* __restrict__ wqs, const float* __restrict__ bqs,
    const float* __restrict__ wks, const float* __restrict__ bks,
    unsigned int* __restrict__ mq, float* __restrict__ mkf) {
  __shared__ float wq_l[4][512];
  __shared__ float wk_l[4][512];
  int b = blockIdx.y;
  int n = blockIdx.x * 256 + threadIdx.x;
  for (int i = threadIdx.x; i < 2048; i += 256) {
    wq_l[i >> 9][i & 511] = wqs[i];
    wk_l[i >> 9][i & 511] = wks[i];
  }
  __syncthreads();
  const float* xp = x + (size_t)b * C_ * N_ + n;
  float sq[4] = {bqs[0], bqs[1], bqs[2], bqs[3]};
  float sk[4] = {bks[0], bks[1], bks[2], bks[3]};
  for (int c = 0; c < 512; c++) {
    float xv = xp[(size_t)c * N_];
#pragma unroll
    for (int r = 0; r < 4; r++) {
      sq[r] = fmaf(wq_l[r][c], xv, sq[r]);
      sk[r] = fmaf(wk_l[r][c], xv, sk[r]);
    }
  }
#pragma unroll
  for (int r = 0; r < 4; r++) {
    float uq = u_q[((size_t)b * 4 + r) * N_ + n];
    float uk = u_k[((size_t)b * 4 + r) * N_ + n];
    sq[r] += -logf(-logf(uq + 1e-10f) + 1e-10f);
    sk[r] += -logf(-logf(uk + 1e-10f) + 1e-10f);
  }
  bool selq = (sq[0] >= sq[1]) && (sq[0] >= sq[2]) && (sq[0] >= sq[3]);
  bool selk = (sk[0] >= sk[1]) && (sk[0] >= sk[2]) && (sk[0] >= sk[3]);
  mq[(size_t)b * N_ + n] = selq ? 1u : 0u;
  mkf[(size_t)b * N_ + n] = selk ? 0.f : -1e30f;
}

// ---------------- BT-form bf16 MFMA GEMM, 128x128 tile, BK=64 ----------------
// out[o][n] = sum_c A[o][c] * Bt[n][c] + bias[o]
// MODE 0: out bf16 at [mat][b][n][o]  (qT/kT/vT);  MODE 1: out f32 at [b][o][n]
template <int MODE>
__global__ __launch_bounds__(256) void k_gemm(
    const unsigned short* __restrict__ Wall, const unsigned short* __restrict__ Bt,
    const float* __restrict__ bias0, const float* __restrict__ bias1,
    const float* __restrict__ bias2, void* __restrict__ outv) {
  __shared__ __align__(16) unsigned short a_lds[128 * 64];
  __shared__ __align__(16) unsigned short b_lds[128 * 64];
  int z = blockIdx.z;
  int mat = (MODE == 0) ? (z >> 3) : 0;
  int b   = (MODE == 0) ? (z & 7) : z;
  const unsigned short* A = Wall + (size_t)mat * 262144;
  const float* bias = (mat == 0) ? bias0 : (mat == 1) ? bias1 : bias2;
  int m0 = blockIdx.y * 128, n0 = blockIdx.x * 128;
  int t = threadIdx.x, wave = t >> 6, lane = t & 63;
  int wr = (wave >> 1) * 64, wc = (wave & 1) * 64;
  const unsigned short* Bb = Bt + ((size_t)b * N_ + n0) * C_;
  f32x4 acc[4][4] = {};
  int srow = t >> 3, spch = t & 7;
  for (int kt = 0; kt < 8; kt++) {
    int k0 = kt * 64;
    __syncthreads();
#pragma unroll
    for (int i = 0; i < 4; i++) {
      int row = srow + i * 32;
      int lch = spch ^ (row & 7);   // pre-swizzled global source, linear LDS dest
      gload16(A + (size_t)(m0 + row) * C_ + k0 + lch * 8,
              (char*)a_lds + wave * 1024 + i * 4096);
      gload16(Bb + (size_t)row * C_ + k0 + lch * 8,
              (char*)b_lds + wave * 1024 + i * 4096);
    }
    __syncthreads();
#pragma unroll
    for (int ks = 0; ks < 2; ks++) {
      bf16x8 af[4], bfr[4];
#pragma unroll
      for (int mi = 0; mi < 4; mi++) {
        int row = wr + mi * 16 + (lane & 15);
        int pch = (ks * 4 + (lane >> 4)) ^ (row & 7);
        af[mi] = *(const bf16x8*)(a_lds + row * 64 + pch * 8);
      }
#pragma unroll
      for (int ni = 0; ni < 4; ni++) {
        int row = wc + ni * 16 + (lane & 15);
        int pch = (ks * 4 + (lane >> 4)) ^ (row & 7);
        bfr[ni] = *(const bf16x8*)(b_lds + row * 64 + pch * 8);
      }
#pragma unroll
      for (int mi = 0; mi < 4; mi++)
#pragma unroll
        for (int ni = 0; ni < 4; ni++)
          acc[mi][ni] = __builtin_amdgcn_mfma_f32_16x16x32_bf16(af[mi], bfr[ni], acc[mi][ni], 0, 0, 0);
    }
  }
  if (MODE == 0) {
    unsigned short* outp = (unsigned short*)outv + (size_t)mat * B_ * N_ * C_ + (size_t)b * N_ * C_;
#pragma unroll
    for (int mi = 0; mi < 4; mi++) {
      int ob = m0 + wr + mi * 16 + ((lane >> 4) << 2);
      float bs[4];
#pragma unroll
      for (int r = 0; r < 4; r++) bs[r] = bias[ob + r];
#pragma unroll
      for (int ni = 0; ni < 4; ni++) {
        int n = n0 + wc + ni * 16 + (lane & 15);
        unsigned short o4[4];
#pragma unroll
        for (int r = 0; r < 4; r++) o4[r] = f2bf(acc[mi][ni][r] + bs[r]);
        unsigned lo = (unsigned)o4[0] | ((unsigned)o4[1] << 16);
        unsigned hi = (unsigned)o4[2] | ((unsigned)o4[3] << 16);
        uint2 u; u.x = lo; u.y = hi;
        *(uint2*)(outp + (size_t)n * C_ + ob) = u;
      }
    }
  } else {
    float* outp = (float*)outv + (size_t)b * C_ * N_;
#pragma unroll
    for (int mi = 0; mi < 4; mi++) {
      int ob = m0 + wr + mi * 16 + ((lane >> 4) << 2);
#pragma unroll
      for (int r = 0; r < 4; r++) {
        float bv = bias[ob + r];
#pragma unroll
        for (int ni = 0; ni < 4; ni++) {
          int n = n0 + wc + ni * 16 + (lane & 15);
          outp[(size_t)(ob + r) * N_ + n] = acc[mi][ni][r] + bv;
        }
      }
    }
  }
}

// ---------------- dense flash attention, per (qtile, h, b) ----------------
__global__ __launch_bounds__(256) void k_attn(
    const unsigned short* __restrict__ qT, const unsigned short* __restrict__ kT,
    const unsigned short* __restrict__ vtr, unsigned short* __restrict__ vnew,
    const unsigned int* __restrict__ mq, const float* __restrict__ mkf) {
  __shared__ __align__(16) unsigned short k_lds[64 * 64];
  __shared__ __align__(16) unsigned short v_lds[64 * 64];
  __shared__ float mk_lds[64];
  __shared__ __align__(16) unsigned short p_lds[4][16 * 72];
  int qt = blockIdx.x, h = blockIdx.y, b = blockIdx.z;
  int t = threadIdx.x, wave = t >> 6, lane = t & 63;
  int q0 = qt * 64 + wave * 16;
  const unsigned short* qp =
      qT + ((size_t)b * N_ + q0 + (lane & 15)) * C_ + h * HD_ + ((lane >> 4) * 8);
  bf16x8 qf0 = *(const bf16x8*)qp;
  bf16x8 qf1 = *(const bf16x8*)(qp + 32);
  float mrow[4], lrow[4];
  f32x4 acc[4];
#pragma unroll
  for (int r = 0; r < 4; r++) { mrow[r] = -1e30f; lrow[r] = 0.f; }
#pragma unroll
  for (int d = 0; d < 4; d++) acc[d] = f32x4{0.f, 0.f, 0.f, 0.f};
  int srow = t >> 3, spch = t & 7;
  for (int kt = 0; kt < 16; kt++) {
    int n0 = kt * 64;
    __syncthreads();
#pragma unroll
    for (int i = 0; i < 2; i++) {
      int row = srow + i * 32;
      int lch = spch ^ (row & 7);
      gload16(kT + ((size_t)b * N_ + n0 + row) * C_ + h * HD_ + lch * 8,
              (char*)k_lds + wave * 1024 + i * 4096);
      gload16(vtr + ((size_t)b * C_ + h * HD_ + row) * N_ + n0 + lch * 8,
              (char*)v_lds + wave * 1024 + i * 4096);
    }
    if (t < 64) mk_lds[t] = mkf[b * N_ + n0 + t];
    __syncthreads();
    // S = (Q K^T) * scale + mask
    f32x4 s[4];
#pragma unroll
    for (int nf = 0; nf < 4; nf++) {
      int row = nf * 16 + (lane & 15);
      f32x4 z = {0.f, 0.f, 0.f, 0.f};
      {
        int pch = ((lane >> 4)) ^ (row & 7);
        bf16x8 kf = *(const bf16x8*)(k_lds + row * 64 + pch * 8);
        z = __builtin_amdgcn_mfma_f32_16x16x32_bf16(qf0, kf, z, 0, 0, 0);
      }
      {
        int pch = (4 + (lane >> 4)) ^ (row & 7);
        bf16x8 kf = *(const bf16x8*)(k_lds + row * 64 + pch * 8);
        z = __builtin_amdgcn_mfma_f32_16x16x32_bf16(qf1, kf, z, 0, 0, 0);
      }
      float mv = mk_lds[nf * 16 + (lane & 15)];
#pragma unroll
      for (int r = 0; r < 4; r++) s[nf][r] = z[r] * 0.125f + mv;
    }
    // online softmax per q-row (row = (lane>>4)*4 + r, spread over 16 lanes)
    float alpha[4];
#pragma unroll
    for (int r = 0; r < 4; r++) {
      float mx = fmaxf(fmaxf(s[0][r], s[1][r]), fmaxf(s[2][r], s[3][r]));
      mx = fmaxf(mx, __shfl_xor(mx, 1));
      mx = fmaxf(mx, __shfl_xor(mx, 2));
      mx = fmaxf(mx, __shfl_xor(mx, 4));
      mx = fmaxf(mx, __shfl_xor(mx, 8));
      float mn = fmaxf(mrow[r], mx);
      alpha[r] = __expf(mrow[r] - mn);
      mrow[r] = mn;
      float rs = 0.f;
      int ql = ((lane >> 4) << 2) + r;
#pragma unroll
      for (int nf = 0; nf < 4; nf++) {
        float sv = s[nf][r];
        float p = (sv < -1e29f) ? 0.f : __expf(sv - mn);
        rs += p;
        p_lds[wave][ql * 72 + nf * 16 + (lane & 15)] = f2bf(p);
      }
      rs += __shfl_xor(rs, 1);
      rs += __shfl_xor(rs, 2);
      rs += __shfl_xor(rs, 4);
      rs += __shfl_xor(rs, 8);
      lrow[r] = lrow[r] * alpha[r] + rs;
    }
    // PV (wave-local P buffer; in-wave lgkmcnt ordering suffices)
    bf16x8 pa0 = *(const bf16x8*)&p_lds[wave][(lane & 15) * 72 + ((lane >> 4) * 8)];
    bf16x8 pa1 = *(const bf16x8*)&p_lds[wave][(lane & 15) * 72 + 32 + ((lane >> 4) * 8)];
#pragma unroll
    for (int df = 0; df < 4; df++) {
#pragma unroll
      for (int r = 0; r < 4; r++) acc[df][r] *= alpha[r];
      int row = df * 16 + (lane & 15);
      int pch0 = ((lane >> 4)) ^ (row & 7);
      int pch1 = (4 + (lane >> 4)) ^ (row & 7);
      bf16x8 vf0 = *(const bf16x8*)(v_lds + row * 64 + pch0 * 8);
      bf16x8 vf1 = *(const bf16x8*)(v_lds + row * 64 + pch1 * 8);
      acc[df] = __builtin_amdgcn_mfma_f32_16x16x32_bf16(pa0, vf0, acc[df], 0, 0, 0);
      acc[df] = __builtin_amdgcn_mfma_f32_16x16x32_bf16(pa1, vf1, acc[df], 0, 0, 0);
    }
  }
  // write out only at selected query rows (v_new in-place over vT)
#pragma unroll
  for (int r = 0; r < 4; r++) {
    int n = q0 + ((lane >> 4) << 2) + r;
    if (mq[b * N_ + n]) {
      float inv = 1.0f / lrow[r];
      unsigned short* dst = vnew + ((size_t)b * N_ + n) * C_ + h * HD_ + (lane & 15);
#pragma unroll
      for (int df = 0; df < 4; df++) dst[df * 16] = f2bf(acc[df][r] * inv);
    }
  }
}

extern "C" void kernel_launch(void* const* d_in, const int* in_sizes, int n_in,
                              void* d_out, int out_size, void* d_ws, size_t ws_size,
                              hipStream_t stream) {
  const float* x   = (const float*)d_in[0];
  const float* u_q = (const float*)d_in[1];
  const float* u_k = (const float*)d_in[2];
  const float* wqs = (const float*)d_in[3];
  const float* bqs = (const float*)d_in[4];
  const float* wks = (const float*)d_in[5];
  const float* bks = (const float*)d_in[6];
  const float* Wq  = (const float*)d_in[7];
  const float* bq  = (const float*)d_in[8];
  const float* Wk  = (const float*)d_in[9];
  const float* bk  = (const float*)d_in[10];
  const float* Wv  = (const float*)d_in[11];
  const float* bv  = (const float*)d_in[12];
  const float* Wp  = (const float*)d_in[13];
  const float* bp  = (const float*)d_in[14];

  char* ws = (char*)d_ws;
  unsigned short* xT  = (unsigned short*)(ws);              // 8,388,608 B
  unsigned short* wbf = (unsigned short*)(ws + 8388608);    // 2,097,152 B (Wq,Wk,Wv,Wp bf16)
  unsigned short* qkv = (unsigned short*)(ws + 10485760);   // 3 x 8,388,608 B (qT,kT,vT)
  unsigned short* qT  = qkv;
  unsigned short* kT  = qkv + (size_t)B_ * N_ * C_;
  unsigned short* vT  = kT + (size_t)B_ * N_ * C_;          // also v_new (in-place)
  unsigned short* vtr = (unsigned short*)(ws + 35651584);   // 8,388,608 B
  unsigned int*   mq  = (unsigned int*)(ws + 44040192);     // 32,768 B
  float*          mkf = (float*)(ws + 44072960);            // 32,768 B

  k_convw<<<dim3(4096), 256, 0, stream>>>(Wq, Wk, Wv, Wp, wbf);
  k_transpose_x<<<dim3(16, 8, 8), 256, 0, stream>>>(x, xT);
  k_mask<<<dim3(4, 8), 256, 0, stream>>>(x, u_q, u_k, wqs, bqs, wks, bks, mq, mkf);
  k_gemm<0><<<dim3(8, 4, 24), 256, 0, stream>>>(wbf, xT, bq, bk, bv, (void*)qkv);
  k_transpose_v<<<dim3(16, 8, 8), 256, 0, stream>>>(vT, vtr);
  k_attn<<<dim3(16, 8, 8), 256, 0, stream>>>(qT, kT, vtr, vT, mq, mkf);
  k_gemm<1><<<dim3(8, 4, 8), 256, 0, stream>>>(wbf + 3 * 262144, vT, bp, bp, bp, d_out);
}

// Round 2
// 216.677 us; speedup vs baseline: 1.1563x; 1.1563x over previous
//
#include <hip/hip_runtime.h>
#include <hip/hip_bf16.h>

#define B_ 8
#define C_ 512
#define N_ 1024
#define HEADS_ 8
#define HD_ 64

using f32x4  = __attribute__((ext_vector_type(4))) float;
using bf16x8 = __attribute__((ext_vector_type(8))) __bf16;

__device__ __forceinline__ unsigned short f2bf(float f) {
  union { float f; unsigned u; } v; v.f = f;
  unsigned r = v.u + 0x7FFFu + ((v.u >> 16) & 1u);
  return (unsigned short)(r >> 16);
}

__device__ __forceinline__ void gload16(const void* g, void* l) {
  __builtin_amdgcn_global_load_lds(
      (const __attribute__((address_space(1))) unsigned int*)g,
      (__attribute__((address_space(3))) unsigned int*)l, 16, 0, 0);
}

// ---------------- weight f32->bf16 ----------------
__global__ __launch_bounds__(256) void k_convw(
    const float* __restrict__ wq, const float* __restrict__ wk,
    const float* __restrict__ wv, const float* __restrict__ wp,
    unsigned short* __restrict__ out) {
  int i = blockIdx.x * 256 + threadIdx.x;
  int mat = i >> 18, idx = i & 262143;
  const float* src = (mat == 0) ? wq : (mat == 1) ? wk : (mat == 2) ? wv : wp;
  out[i] = f2bf(src[idx]);
}

// ---------------- x [b][c][n] f32 -> xT [b][n][c] bf16 ----------------
__global__ __launch_bounds__(256) void k_transpose_x(
    const float* __restrict__ x, unsigned short* __restrict__ xT) {
  __shared__ float tile[64][65];
  int n0 = blockIdx.x * 64, c0 = blockIdx.y * 64, b = blockIdx.z;
  int t = threadIdx.x, tr = t >> 2, tc = (t & 3) * 16;
  const float* src = x + ((size_t)b * C_ + c0) * N_ + n0;
#pragma unroll
  for (int i = 0; i < 4; i++) {
    float4 v4 = *(const float4*)(src + (size_t)tr * N_ + tc + i * 4);
    tile[tr][tc + i * 4 + 0] = v4.x; tile[tr][tc + i * 4 + 1] = v4.y;
    tile[tr][tc + i * 4 + 2] = v4.z; tile[tr][tc + i * 4 + 3] = v4.w;
  }
  __syncthreads();
  unsigned short* dst = xT + ((size_t)b * N_ + n0) * C_ + c0;
#pragma unroll
  for (int i = 0; i < 4; i++) {
    unsigned short o4[4];
#pragma unroll
    for (int j = 0; j < 4; j++) o4[j] = f2bf(tile[tc + i * 4 + j][tr]);
    unsigned lo = (unsigned)o4[0] | ((unsigned)o4[1] << 16);
    unsigned hi = (unsigned)o4[2] | ((unsigned)o4[3] << 16);
    uint2 u; u.x = lo; u.y = hi;
    *(uint2*)(dst + (size_t)tr * C_ + tc + i * 4) = u;
  }
}

// ---------------- gumbel argmax selection flags (f32, identical arith to R1) ----------------
__global__ __launch_bounds__(256) void k_mask(
    const float* __restrict__ x, const float* __restrict__ u_q, const float* __restrict__ u_k,
    const float* __restrict__ wqs, const float* __restrict__ bqs,
    const float* __restrict__ wks, const float* __restrict__ bks,
    unsigned int* __restrict__ sel) {   // sel[0][b][n]=q, sel[1][b][n]=k
  __shared__ float wq_l[4][512];
  __shared__ float wk_l[4][512];
  int b = blockIdx.y;
  int n = blockIdx.x * 256 + threadIdx.x;
  for (int i = threadIdx.x; i < 2048; i += 256) {
    wq_l[i >> 9][i & 511] = wqs[i];
    wk_l[i >> 9][i & 511] = wks[i];
  }
  __syncthreads();
  const float* xp = x + (size_t)b * C_ * N_ + n;
  float sq[4] = {bqs[0], bqs[1], bqs[2], bqs[3]};
  float sk[4] = {bks[0], bks[1], bks[2], bks[3]};
  for (int c = 0; c < 512; c++) {
    float xv = xp[(size_t)c * N_];
#pragma unroll
    for (int r = 0; r < 4; r++) {
      sq[r] = fmaf(wq_l[r][c], xv, sq[r]);
      sk[r] = fmaf(wk_l[r][c], xv, sk[r]);
    }
  }
#pragma unroll
  for (int r = 0; r < 4; r++) {
    float uq = u_q[((size_t)b * 4 + r) * N_ + n];
    float uk = u_k[((size_t)b * 4 + r) * N_ + n];
    sq[r] += -logf(-logf(uq + 1e-10f) + 1e-10f);
    sk[r] += -logf(-logf(uk + 1e-10f) + 1e-10f);
  }
  bool selq = (sq[0] >= sq[1]) && (sq[0] >= sq[2]) && (sq[0] >= sq[3]);
  bool selk = (sk[0] >= sk[1]) && (sk[0] >= sk[2]) && (sk[0] >= sk[3]);
  sel[(size_t)b * N_ + n] = selq ? 1u : 0u;
  sel[(size_t)(B_ + b) * N_ + n] = selk ? 1u : 0u;
}

// ---------------- compaction scan: flags -> index lists + counts ----------------
__global__ __launch_bounds__(1024) void k_scan(
    const unsigned int* __restrict__ sel, unsigned int* __restrict__ idx,
    unsigned int* __restrict__ cnt) {
  int which = blockIdx.x, b = blockIdx.y;
  const unsigned int* s = sel + ((size_t)which * B_ + b) * N_;
  unsigned int* ip = idx + ((size_t)which * B_ + b) * N_;
  int t = threadIdx.x, lane = t & 63, w = t >> 6;   // 16 waves
  __shared__ unsigned int wtot[16], woff[16], totsh;
  unsigned int f = s[t];
  unsigned long long bal = __ballot(f != 0);
  unsigned int wpre = __popcll(bal & ((1ull << lane) - 1ull));
  if (lane == 0) wtot[w] = (unsigned int)__popcll(bal);
  __syncthreads();
  if (t == 0) {
    unsigned int acc = 0;
#pragma unroll
    for (int i = 0; i < 16; i++) { woff[i] = acc; acc += wtot[i]; }
    totsh = acc;
    cnt[which * B_ + b] = acc;
  }
  __syncthreads();
  unsigned int tot = totsh;
  if (f) ip[woff[w] + wpre] = (unsigned int)t;
  if (t >= (int)tot) ip[t] = 0u;   // safe pad rows (disjoint range)
}

// ---------------- BT-form bf16 MFMA GEMM, 128x128 tile, BK=64 ----------------
// MODE 0: mat 0=q (gathered rows via idx[0], compact out), 1=k (idx[1]), 2=v dense.
//         out bf16 [mat][b][row][o].
// MODE 1: dense, out f32 [b][o][n].
template <int MODE>
__global__ __launch_bounds__(256) void k_gemm(
    const unsigned short* __restrict__ Wall, const unsigned short* __restrict__ Bt,
    const float* __restrict__ bias0, const float* __restrict__ bias1,
    const float* __restrict__ bias2,
    const unsigned int* __restrict__ idx, const unsigned int* __restrict__ cnt,
    void* __restrict__ outv) {
  __shared__ __align__(16) unsigned short a_lds[128 * 64];
  __shared__ __align__(16) unsigned short b_lds[128 * 64];
  int z = blockIdx.z;
  int mat = (MODE == 0) ? (z >> 3) : 0;
  int b   = (MODE == 0) ? (z & 7) : z;
  int n0 = blockIdx.x * 128;
  if (MODE == 0 && mat < 2 && n0 >= (int)cnt[mat * B_ + b]) return;  // uniform exit
  const unsigned short* A = Wall + (size_t)mat * 262144;
  const float* bias = (mat == 0) ? bias0 : (mat == 1) ? bias1 : bias2;
  int m0 = blockIdx.y * 128;
  int t = threadIdx.x, wave = t >> 6, lane = t & 63;
  int wr = (wave >> 1) * 64, wc = (wave & 1) * 64;
  f32x4 acc[4][4] = {};
  int srow = t >> 3, spch = t & 7;
  int lch = spch ^ (srow & 7);               // pre-swizzled global source, linear LDS dest
  const unsigned short* aptr[4];
  const unsigned short* bptr[4];
#pragma unroll
  for (int i = 0; i < 4; i++) {
    int row = srow + i * 32;
    aptr[i] = A + (size_t)(m0 + row) * C_ + lch * 8;
    int grow = n0 + row;
    int srcr = (MODE == 0 && mat < 2) ? (int)idx[((size_t)mat * B_ + b) * N_ + grow] : grow;
    bptr[i] = Bt + ((size_t)b * N_ + srcr) * C_ + lch * 8;
  }
  for (int kt = 0; kt < 8; kt++) {
    int k0 = kt * 64;
    __syncthreads();
#pragma unroll
    for (int i = 0; i < 4; i++) {
      gload16(aptr[i] + k0, (char*)a_lds + wave * 1024 + i * 4096);
      gload16(bptr[i] + k0, (char*)b_lds + wave * 1024 + i * 4096);
    }
    __syncthreads();
#pragma unroll
    for (int ks = 0; ks < 2; ks++) {
      bf16x8 af[4], bfr[4];
#pragma unroll
      for (int mi = 0; mi < 4; mi++) {
        int row = wr + mi * 16 + (lane & 15);
        int pch = (ks * 4 + (lane >> 4)) ^ (row & 7);
        af[mi] = *(const bf16x8*)(a_lds + row * 64 + pch * 8);
      }
#pragma unroll
      for (int ni = 0; ni < 4; ni++) {
        int row = wc + ni * 16 + (lane & 15);
        int pch = (ks * 4 + (lane >> 4)) ^ (row & 7);
        bfr[ni] = *(const bf16x8*)(b_lds + row * 64 + pch * 8);
      }
#pragma unroll
      for (int mi = 0; mi < 4; mi++)
#pragma unroll
        for (int ni = 0; ni < 4; ni++)
          acc[mi][ni] = __builtin_amdgcn_mfma_f32_16x16x32_bf16(af[mi], bfr[ni], acc[mi][ni], 0, 0, 0);
    }
  }
  if (MODE == 0) {
    unsigned short* outp = (unsigned short*)outv + (size_t)mat * B_ * N_ * C_ + (size_t)b * N_ * C_;
#pragma unroll
    for (int mi = 0; mi < 4; mi++) {
      int ob = m0 + wr + mi * 16 + ((lane >> 4) << 2);
      float bs[4];
#pragma unroll
      for (int r = 0; r < 4; r++) bs[r] = bias[ob + r];
#pragma unroll
      for (int ni = 0; ni < 4; ni++) {
        int n = n0 + wc + ni * 16 + (lane & 15);
        unsigned short o4[4];
#pragma unroll
        for (int r = 0; r < 4; r++) o4[r] = f2bf(acc[mi][ni][r] + bs[r]);
        unsigned lo = (unsigned)o4[0] | ((unsigned)o4[1] << 16);
        unsigned hi = (unsigned)o4[2] | ((unsigned)o4[3] << 16);
        uint2 u; u.x = lo; u.y = hi;
        *(uint2*)(outp + (size_t)n * C_ + ob) = u;
      }
    }
  } else {
    float* outp = (float*)outv + (size_t)b * C_ * N_;
#pragma unroll
    for (int mi = 0; mi < 4; mi++) {
      int ob = m0 + wr + mi * 16 + ((lane >> 4) << 2);
#pragma unroll
      for (int r = 0; r < 4; r++) {
        float bv = bias[ob + r];
#pragma unroll
        for (int ni = 0; ni < 4; ni++) {
          int n = n0 + wc + ni * 16 + (lane & 15);
          outp[(size_t)(ob + r) * N_ + n] = acc[mi][ni][r] + bv;
        }
      }
    }
  }
}

// ---------------- gather+transpose: vctr[b][c][jj] = vT[b][kidx[jj]][c], 0 for jj>=nk ----------------
__global__ __launch_bounds__(256) void k_gather_vt(
    const unsigned short* __restrict__ vT, const unsigned int* __restrict__ idx,
    const unsigned int* __restrict__ cnt, unsigned short* __restrict__ vctr) {
  int b = blockIdx.z;
  unsigned int nk = cnt[B_ + b];
  int j0 = blockIdx.x * 64;
  if (j0 >= (int)nk) return;
  int c0 = blockIdx.y * 64;
  __shared__ unsigned short tile[64][72];
  int t = threadIdx.x, tr = t >> 2, tc = (t & 3) * 16;
  int jj = j0 + tr;
  bool valid = jj < (int)nk;
  unsigned int srow = valid ? idx[((size_t)B_ + b) * N_ + jj] : 0u;
  const unsigned short* src = vT + ((size_t)b * N_ + srow) * C_ + c0;
#pragma unroll
  for (int i = 0; i < 4; i++) {
    ushort4 v4 = {0, 0, 0, 0};
    if (valid) v4 = *(const ushort4*)(src + tc + i * 4);
    tile[tr][tc + i * 4 + 0] = v4.x; tile[tr][tc + i * 4 + 1] = v4.y;
    tile[tr][tc + i * 4 + 2] = v4.z; tile[tr][tc + i * 4 + 3] = v4.w;
  }
  __syncthreads();
  unsigned short* dst = vctr + ((size_t)b * C_ + c0) * N_ + j0;
#pragma unroll
  for (int i = 0; i < 4; i++) {
    unsigned short o4[4];
#pragma unroll
    for (int j = 0; j < 4; j++) o4[j] = tile[tc + i * 4 + j][tr];
    unsigned lo = (unsigned)o4[0] | ((unsigned)o4[1] << 16);
    unsigned hi = (unsigned)o4[2] | ((unsigned)o4[3] << 16);
    uint2 u; u.x = lo; u.y = hi;
    *(uint2*)(dst + (size_t)tr * N_ + tc + i * 4) = u;
  }
}

// ---------------- compact flash attention over selected q/k ----------------
__global__ __launch_bounds__(256) void k_attn(
    const unsigned short* __restrict__ qc, const unsigned short* __restrict__ kc,
    const unsigned short* __restrict__ vctr, unsigned short* __restrict__ vnew,
    const unsigned int* __restrict__ idx, const unsigned int* __restrict__ cnt) {
  __shared__ __align__(16) unsigned short k_lds[64 * 64];
  __shared__ __align__(16) unsigned short v_lds[64 * 64];
  __shared__ __align__(16) unsigned short p_lds[4][16 * 72];
  int qt = blockIdx.x, h = blockIdx.y, b = blockIdx.z;
  unsigned int nq = cnt[b], nk = cnt[B_ + b];
  if (qt * 64 >= (int)nq) return;                      // uniform exit
  int t = threadIdx.x, wave = t >> 6, lane = t & 63;
  int q0 = qt * 64 + wave * 16;
  const unsigned short* qp =
      qc + ((size_t)b * N_ + q0 + (lane & 15)) * C_ + h * HD_ + ((lane >> 4) * 8);
  bf16x8 qf0 = *(const bf16x8*)qp;
  bf16x8 qf1 = *(const bf16x8*)(qp + 32);
  float mrow[4], lrow[4];
  f32x4 acc[4];
#pragma unroll
  for (int r = 0; r < 4; r++) { mrow[r] = -1e30f; lrow[r] = 0.f; }
#pragma unroll
  for (int d = 0; d < 4; d++) acc[d] = f32x4{0.f, 0.f, 0.f, 0.f};
  int srow = t >> 3, spch = t & 7;
  int nkt = ((int)nk + 63) >> 6;
  for (int kt = 0; kt < nkt; kt++) {
    int n0 = kt * 64;
    __syncthreads();
#pragma unroll
    for (int i = 0; i < 2; i++) {
      int row = srow + i * 32;
      int lch = spch ^ (row & 7);
      gload16(kc + ((size_t)b * N_ + n0 + row) * C_ + h * HD_ + lch * 8,
              (char*)k_lds + wave * 1024 + i * 4096);
      gload16(vctr + ((size_t)b * C_ + h * HD_ + row) * N_ + n0 + lch * 8,
              (char*)v_lds + wave * 1024 + i * 4096);
    }
    __syncthreads();
    // S = (Q K^T) * scale + pad mask
    f32x4 s[4];
#pragma unroll
    for (int nf = 0; nf < 4; nf++) {
      int row = nf * 16 + (lane & 15);
      f32x4 z = {0.f, 0.f, 0.f, 0.f};
      {
        int pch = ((lane >> 4)) ^ (row & 7);
        bf16x8 kf = *(const bf16x8*)(k_lds + row * 64 + pch * 8);
        z = __builtin_amdgcn_mfma_f32_16x16x32_bf16(qf0, kf, z, 0, 0, 0);
      }
      {
        int pch = (4 + (lane >> 4)) ^ (row & 7);
        bf16x8 kf = *(const bf16x8*)(k_lds + row * 64 + pch * 8);
        z = __builtin_amdgcn_mfma_f32_16x16x32_bf16(qf1, kf, z, 0, 0, 0);
      }
      float mv = ((n0 + row) < (int)nk) ? 0.f : -1e30f;
#pragma unroll
      for (int r = 0; r < 4; r++) s[nf][r] = z[r] * 0.125f + mv;
    }
    // online softmax per q-row
    float alpha[4];
#pragma unroll
    for (int r = 0; r < 4; r++) {
      float mx = fmaxf(fmaxf(s[0][r], s[1][r]), fmaxf(s[2][r], s[3][r]));
      mx = fmaxf(mx, __shfl_xor(mx, 1));
      mx = fmaxf(mx, __shfl_xor(mx, 2));
      mx = fmaxf(mx, __shfl_xor(mx, 4));
      mx = fmaxf(mx, __shfl_xor(mx, 8));
      float mn = fmaxf(mrow[r], mx);
      alpha[r] = __expf(mrow[r] - mn);
      mrow[r] = mn;
      float rs = 0.f;
      int ql = ((lane >> 4) << 2) + r;
#pragma unroll
      for (int nf = 0; nf < 4; nf++) {
        float sv = s[nf][r];
        float p = (sv < -1e29f) ? 0.f : __expf(sv - mn);
        rs += p;
        p_lds[wave][ql * 72 + nf * 16 + (lane & 15)] = f2bf(p);
      }
      rs += __shfl_xor(rs, 1);
      rs += __shfl_xor(rs, 2);
      rs += __shfl_xor(rs, 4);
      rs += __shfl_xor(rs, 8);
      lrow[r] = lrow[r] * alpha[r] + rs;
    }
    // PV (wave-local P buffer; in-wave lgkmcnt ordering suffices)
    bf16x8 pa0 = *(const bf16x8*)&p_lds[wave][(lane & 15) * 72 + ((lane >> 4) * 8)];
    bf16x8 pa1 = *(const bf16x8*)&p_lds[wave][(lane & 15) * 72 + 32 + ((lane >> 4) * 8)];
#pragma unroll
    for (int df = 0; df < 4; df++) {
#pragma unroll
      for (int r = 0; r < 4; r++) acc[df][r] *= alpha[r];
      int row = df * 16 + (lane & 15);
      int pch0 = ((lane >> 4)) ^ (row & 7);
      int pch1 = (4 + (lane >> 4)) ^ (row & 7);
      bf16x8 vf0 = *(const bf16x8*)(v_lds + row * 64 + pch0 * 8);
      bf16x8 vf1 = *(const bf16x8*)(v_lds + row * 64 + pch1 * 8);
      acc[df] = __builtin_amdgcn_mfma_f32_16x16x32_bf16(pa0, vf0, acc[df], 0, 0, 0);
      acc[df] = __builtin_amdgcn_mfma_f32_16x16x32_bf16(pa1, vf1, acc[df], 0, 0, 0);
    }
  }
  // scatter output rows back into v_new at original positions
#pragma unroll
  for (int r = 0; r < 4; r++) {
    int ii = q0 + ((lane >> 4) << 2) + r;
    if (ii < (int)nq) {
      unsigned int qrow = idx[(size_t)b * N_ + ii];
      float inv = 1.0f / lrow[r];
      unsigned short* dst = vnew + ((size_t)b * N_ + qrow) * C_ + h * HD_ + (lane & 15);
#pragma unroll
      for (int df = 0; df < 4; df++) dst[df * 16] = f2bf(acc[df][r] * inv);
    }
  }
}

extern "C" void kernel_launch(void* const* d_in, const int* in_sizes, int n_in,
                              void* d_out, int out_size, void* d_ws, size_t ws_size,
                              hipStream_t stream) {
  const float* x   = (const float*)d_in[0];
  const float* u_q = (const float*)d_in[1];
  const float* u_k = (const float*)d_in[2];
  const float* wqs = (const float*)d_in[3];
  const float* bqs = (const float*)d_in[4];
  const float* wks = (const float*)d_in[5];
  const float* bks = (const float*)d_in[6];
  const float* Wq  = (const float*)d_in[7];
  const float* bq  = (const float*)d_in[8];
  const float* Wk  = (const float*)d_in[9];
  const float* bk  = (const float*)d_in[10];
  const float* Wv  = (const float*)d_in[11];
  const float* bv  = (const float*)d_in[12];
  const float* Wp  = (const float*)d_in[13];
  const float* bp  = (const float*)d_in[14];

  char* ws = (char*)d_ws;
  unsigned short* xT   = (unsigned short*)(ws);              // 8 MB
  unsigned short* wbf  = (unsigned short*)(ws + 8388608);    // 2 MB
  unsigned short* qkv  = (unsigned short*)(ws + 10485760);   // 3 x 8 MB (qc, kc, vT)
  unsigned short* qc   = qkv;
  unsigned short* kc   = qkv + (size_t)B_ * N_ * C_;
  unsigned short* vT   = kc + (size_t)B_ * N_ * C_;          // dense v; v_new in-place
  unsigned short* vctr = (unsigned short*)(ws + 35651584);   // 8 MB
  unsigned int*   sel  = (unsigned int*)(ws + 44040192);     // 64 KB [2][B][N]
  unsigned int*   idx  = (unsigned int*)(ws + 44105728);     // 64 KB [2][B][N]
  unsigned int*   cnt  = (unsigned int*)(ws + 44171264);     // 64 B  [2][B]

  k_convw<<<dim3(4096), 256, 0, stream>>>(Wq, Wk, Wv, Wp, wbf);
  k_transpose_x<<<dim3(16, 8, 8), 256, 0, stream>>>(x, xT);
  k_mask<<<dim3(4, 8), 256, 0, stream>>>(x, u_q, u_k, wqs, bqs, wks, bks, sel);
  k_scan<<<dim3(2, 8), 1024, 0, stream>>>(sel, idx, cnt);
  k_gemm<0><<<dim3(8, 4, 24), 256, 0, stream>>>(wbf, xT, bq, bk, bv, idx, cnt, (void*)qkv);
  k_gather_vt<<<dim3(16, 8, 8), 256, 0, stream>>>(vT, idx, cnt, vctr);
  k_attn<<<dim3(16, 8, 8), 256, 0, stream>>>(qc, kc, vctr, vT, idx, cnt);
  k_gemm<1><<<dim3(8, 4, 8), 256, 0, stream>>>(wbf + 3 * 262144, vT, bp, bp, bp, idx, cnt, d_out);
}

// Round 3
// 177.686 us; speedup vs baseline: 1.4100x; 1.2194x over previous
//
#include <hip/hip_runtime.h>
#include <hip/hip_bf16.h>

#define B_ 8
#define C_ 512
#define N_ 1024
#define HEADS_ 8
#define HD_ 64

using f32x4  = __attribute__((ext_vector_type(4))) float;
using bf16x8 = __attribute__((ext_vector_type(8))) __bf16;

__device__ __forceinline__ unsigned short f2bf(float f) {
  union { float f; unsigned u; } v; v.f = f;
  unsigned r = v.u + 0x7FFFu + ((v.u >> 16) & 1u);
  return (unsigned short)(r >> 16);
}

__device__ __forceinline__ void gload16(const void* g, void* l) {
  __builtin_amdgcn_global_load_lds(
      (const __attribute__((address_space(1))) unsigned int*)g,
      (__attribute__((address_space(3))) unsigned int*)l, 16, 0, 0);
}

// ---------------- weight f32->bf16 ----------------
__global__ __launch_bounds__(256) void k_convw(
    const float* __restrict__ wq, const float* __restrict__ wk,
    const float* __restrict__ wv, const float* __restrict__ wp,
    unsigned short* __restrict__ out) {
  int i = blockIdx.x * 256 + threadIdx.x;
  int mat = i >> 18, idx = i & 262143;
  const float* src = (mat == 0) ? wq : (mat == 1) ? wk : (mat == 2) ? wv : wp;
  out[i] = f2bf(src[idx]);
}

// ---------------- x [b][c][n] f32 -> xT [b][n][c] bf16 ----------------
__global__ __launch_bounds__(256) void k_transpose_x(
    const float* __restrict__ x, unsigned short* __restrict__ xT) {
  __shared__ float tile[64][65];
  int n0 = blockIdx.x * 64, c0 = blockIdx.y * 64, b = blockIdx.z;
  int t = threadIdx.x, tr = t >> 2, tc = (t & 3) * 16;
  const float* src = x + ((size_t)b * C_ + c0) * N_ + n0;
#pragma unroll
  for (int i = 0; i < 4; i++) {
    float4 v4 = *(const float4*)(src + (size_t)tr * N_ + tc + i * 4);
    tile[tr][tc + i * 4 + 0] = v4.x; tile[tr][tc + i * 4 + 1] = v4.y;
    tile[tr][tc + i * 4 + 2] = v4.z; tile[tr][tc + i * 4 + 3] = v4.w;
  }
  __syncthreads();
  unsigned short* dst = xT + ((size_t)b * N_ + n0) * C_ + c0;
#pragma unroll
  for (int i = 0; i < 4; i++) {
    unsigned short o4[4];
#pragma unroll
    for (int j = 0; j < 4; j++) o4[j] = f2bf(tile[tc + i * 4 + j][tr]);
    unsigned lo = (unsigned)o4[0] | ((unsigned)o4[1] << 16);
    unsigned hi = (unsigned)o4[2] | ((unsigned)o4[3] << 16);
    uint2 u; u.x = lo; u.y = hi;
    *(uint2*)(dst + (size_t)tr * C_ + tc + i * 4) = u;
  }
}

// ---------------- gumbel argmax selection flags (f32; split-C parallel) ----------------
// grid (N/32, B), 256 threads: thread = (chunk=t>>5 of 8, nl=t&31)
__global__ __launch_bounds__(256) void k_mask(
    const float* __restrict__ x, const float* __restrict__ u_q, const float* __restrict__ u_k,
    const float* __restrict__ wqs, const float* __restrict__ bqs,
    const float* __restrict__ wks, const float* __restrict__ bks,
    unsigned int* __restrict__ sel) {   // sel[0][b][n]=q, sel[1][b][n]=k
  __shared__ float wq_l[4][512];
  __shared__ float wk_l[4][512];
  __shared__ float part[8 * 32 * 9];   // [chunk][nl][8 partials], stride 9 pad
  int b = blockIdx.y;
  int n0 = blockIdx.x * 32;
  int t = threadIdx.x, nl = t & 31, ch = t >> 5;
  for (int i = t; i < 2048; i += 256) {
    wq_l[i >> 9][i & 511] = wqs[i];
    wk_l[i >> 9][i & 511] = wks[i];
  }
  __syncthreads();
  int cbase = ch * 64;
  const float* xp = x + ((size_t)b * C_ + cbase) * N_ + n0 + nl;
  float sq[4] = {0.f, 0.f, 0.f, 0.f};
  float sk[4] = {0.f, 0.f, 0.f, 0.f};
  for (int c = 0; c < 64; c++) {
    float xv = xp[(size_t)c * N_];
#pragma unroll
    for (int r = 0; r < 4; r++) {
      sq[r] = fmaf(wq_l[r][cbase + c], xv, sq[r]);
      sk[r] = fmaf(wk_l[r][cbase + c], xv, sk[r]);
    }
  }
  float* pp = part + (ch * 32 + nl) * 9;
#pragma unroll
  for (int r = 0; r < 4; r++) { pp[r] = sq[r]; pp[4 + r] = sk[r]; }
  __syncthreads();
  if (t < 32) {
    int n = n0 + t;
    float fq[4], fk[4];
#pragma unroll
    for (int r = 0; r < 4; r++) { fq[r] = bqs[r]; fk[r] = bks[r]; }
#pragma unroll
    for (int c2 = 0; c2 < 8; c2++) {
      const float* q2 = part + (c2 * 32 + t) * 9;
#pragma unroll
      for (int r = 0; r < 4; r++) { fq[r] += q2[r]; fk[r] += q2[4 + r]; }
    }
#pragma unroll
    for (int r = 0; r < 4; r++) {
      float uq = u_q[((size_t)b * 4 + r) * N_ + n];
      float uk = u_k[((size_t)b * 4 + r) * N_ + n];
      fq[r] += -logf(-logf(uq + 1e-10f) + 1e-10f);
      fk[r] += -logf(-logf(uk + 1e-10f) + 1e-10f);
    }
    bool selq = (fq[0] >= fq[1]) && (fq[0] >= fq[2]) && (fq[0] >= fq[3]);
    bool selk = (fk[0] >= fk[1]) && (fk[0] >= fk[2]) && (fk[0] >= fk[3]);
    sel[(size_t)b * N_ + n] = selq ? 1u : 0u;
    sel[(size_t)(B_ + b) * N_ + n] = selk ? 1u : 0u;
  }
}

// ---------------- compaction scan: flags -> index lists + counts ----------------
__global__ __launch_bounds__(1024) void k_scan(
    const unsigned int* __restrict__ sel, unsigned int* __restrict__ idx,
    unsigned int* __restrict__ cnt) {
  int which = blockIdx.x, b = blockIdx.y;
  const unsigned int* s = sel + ((size_t)which * B_ + b) * N_;
  unsigned int* ip = idx + ((size_t)which * B_ + b) * N_;
  int t = threadIdx.x, lane = t & 63, w = t >> 6;   // 16 waves
  __shared__ unsigned int wtot[16], woff[16], totsh;
  unsigned int f = s[t];
  unsigned long long bal = __ballot(f != 0);
  unsigned int wpre = __popcll(bal & ((1ull << lane) - 1ull));
  if (lane == 0) wtot[w] = (unsigned int)__popcll(bal);
  __syncthreads();
  if (t == 0) {
    unsigned int acc = 0;
#pragma unroll
    for (int i = 0; i < 16; i++) { woff[i] = acc; acc += wtot[i]; }
    totsh = acc;
    cnt[which * B_ + b] = acc;
  }
  __syncthreads();
  unsigned int tot = totsh;
  if (f) ip[woff[w] + wpre] = (unsigned int)t;
  if (t >= (int)tot) ip[t] = 0u;   // safe pad rows (disjoint range)
}

// ---------------- BT-form bf16 MFMA GEMM, 128x128 tile, BK=64 ----------------
// MODE 0: mat 0=q (gathered rows via idx[0], compact out), 1=k (idx[1]), 2=v dense.
//         out bf16 [mat][b][row][o].
// MODE 1: dense, out f32 [b][o][n].
template <int MODE>
__global__ __launch_bounds__(256) void k_gemm(
    const unsigned short* __restrict__ Wall, const unsigned short* __restrict__ Bt,
    const float* __restrict__ bias0, const float* __restrict__ bias1,
    const float* __restrict__ bias2,
    const unsigned int* __restrict__ idx, const unsigned int* __restrict__ cnt,
    void* __restrict__ outv) {
  __shared__ __align__(16) unsigned short a_lds[128 * 64];
  __shared__ __align__(16) unsigned short b_lds[128 * 64];
  int z = blockIdx.z;
  int mat = (MODE == 0) ? (z >> 3) : 0;
  int b   = (MODE == 0) ? (z & 7) : z;
  int n0 = blockIdx.x * 128;
  if (MODE == 0 && mat < 2 && n0 >= (int)cnt[mat * B_ + b]) return;  // uniform exit
  const unsigned short* A = Wall + (size_t)mat * 262144;
  const float* bias = (mat == 0) ? bias0 : (mat == 1) ? bias1 : bias2;
  int m0 = blockIdx.y * 128;
  int t = threadIdx.x, wave = t >> 6, lane = t & 63;
  int wr = (wave >> 1) * 64, wc = (wave & 1) * 64;
  f32x4 acc[4][4] = {};
  int srow = t >> 3, spch = t & 7;
  int lch = spch ^ (srow & 7);               // pre-swizzled global source, linear LDS dest
  const unsigned short* aptr[4];
  const unsigned short* bptr[4];
#pragma unroll
  for (int i = 0; i < 4; i++) {
    int row = srow + i * 32;
    aptr[i] = A + (size_t)(m0 + row) * C_ + lch * 8;
    int grow = n0 + row;
    int srcr = (MODE == 0 && mat < 2) ? (int)idx[((size_t)mat * B_ + b) * N_ + grow] : grow;
    bptr[i] = Bt + ((size_t)b * N_ + srcr) * C_ + lch * 8;
  }
  for (int kt = 0; kt < 8; kt++) {
    int k0 = kt * 64;
    __syncthreads();
#pragma unroll
    for (int i = 0; i < 4; i++) {
      gload16(aptr[i] + k0, (char*)a_lds + wave * 1024 + i * 4096);
      gload16(bptr[i] + k0, (char*)b_lds + wave * 1024 + i * 4096);
    }
    __syncthreads();
#pragma unroll
    for (int ks = 0; ks < 2; ks++) {
      bf16x8 af[4], bfr[4];
#pragma unroll
      for (int mi = 0; mi < 4; mi++) {
        int row = wr + mi * 16 + (lane & 15);
        int pch = (ks * 4 + (lane >> 4)) ^ (row & 7);
        af[mi] = *(const bf16x8*)(a_lds + row * 64 + pch * 8);
      }
#pragma unroll
      for (int ni = 0; ni < 4; ni++) {
        int row = wc + ni * 16 + (lane & 15);
        int pch = (ks * 4 + (lane >> 4)) ^ (row & 7);
        bfr[ni] = *(const bf16x8*)(b_lds + row * 64 + pch * 8);
      }
#pragma unroll
      for (int mi = 0; mi < 4; mi++)
#pragma unroll
        for (int ni = 0; ni < 4; ni++)
          acc[mi][ni] = __builtin_amdgcn_mfma_f32_16x16x32_bf16(af[mi], bfr[ni], acc[mi][ni], 0, 0, 0);
    }
  }
  if (MODE == 0) {
    unsigned short* outp = (unsigned short*)outv + (size_t)mat * B_ * N_ * C_ + (size_t)b * N_ * C_;
#pragma unroll
    for (int mi = 0; mi < 4; mi++) {
      int ob = m0 + wr + mi * 16 + ((lane >> 4) << 2);
      float bs[4];
#pragma unroll
      for (int r = 0; r < 4; r++) bs[r] = bias[ob + r];
#pragma unroll
      for (int ni = 0; ni < 4; ni++) {
        int n = n0 + wc + ni * 16 + (lane & 15);
        unsigned short o4[4];
#pragma unroll
        for (int r = 0; r < 4; r++) o4[r] = f2bf(acc[mi][ni][r] + bs[r]);
        unsigned lo = (unsigned)o4[0] | ((unsigned)o4[1] << 16);
        unsigned hi = (unsigned)o4[2] | ((unsigned)o4[3] << 16);
        uint2 u; u.x = lo; u.y = hi;
        *(uint2*)(outp + (size_t)n * C_ + ob) = u;
      }
    }
  } else {
    float* outp = (float*)outv + (size_t)b * C_ * N_;
#pragma unroll
    for (int mi = 0; mi < 4; mi++) {
      int ob = m0 + wr + mi * 16 + ((lane >> 4) << 2);
#pragma unroll
      for (int r = 0; r < 4; r++) {
        float bv = bias[ob + r];
#pragma unroll
        for (int ni = 0; ni < 4; ni++) {
          int n = n0 + wc + ni * 16 + (lane & 15);
          outp[(size_t)(ob + r) * N_ + n] = acc[mi][ni][r] + bv;
        }
      }
    }
  }
}

// ---------------- gather+transpose: vctr[b][c][jj] = vT[b][kidx[jj]][c], 0 for jj>=nk ----------------
__global__ __launch_bounds__(256) void k_gather_vt(
    const unsigned short* __restrict__ vT, const unsigned int* __restrict__ idx,
    const unsigned int* __restrict__ cnt, unsigned short* __restrict__ vctr) {
  int b = blockIdx.z;
  unsigned int nk = cnt[B_ + b];
  int j0 = blockIdx.x * 64;
  if (j0 >= (int)nk) return;
  int c0 = blockIdx.y * 64;
  __shared__ unsigned short tile[64][72];
  int t = threadIdx.x, tr = t >> 2, tc = (t & 3) * 16;
  int jj = j0 + tr;
  bool valid = jj < (int)nk;
  unsigned int srow = valid ? idx[((size_t)B_ + b) * N_ + jj] : 0u;
  const unsigned short* src = vT + ((size_t)b * N_ + srow) * C_ + c0;
#pragma unroll
  for (int i = 0; i < 4; i++) {
    ushort4 v4 = {0, 0, 0, 0};
    if (valid) v4 = *(const ushort4*)(src + tc + i * 4);
    tile[tr][tc + i * 4 + 0] = v4.x; tile[tr][tc + i * 4 + 1] = v4.y;
    tile[tr][tc + i * 4 + 2] = v4.z; tile[tr][tc + i * 4 + 3] = v4.w;
  }
  __syncthreads();
  unsigned short* dst = vctr + ((size_t)b * C_ + c0) * N_ + j0;
#pragma unroll
  for (int i = 0; i < 4; i++) {
    unsigned short o4[4];
#pragma unroll
    for (int j = 0; j < 4; j++) o4[j] = tile[tc + i * 4 + j][tr];
    unsigned lo = (unsigned)o4[0] | ((unsigned)o4[1] << 16);
    unsigned hi = (unsigned)o4[2] | ((unsigned)o4[3] << 16);
    uint2 u; u.x = lo; u.y = hi;
    *(uint2*)(dst + (size_t)tr * N_ + tc + i * 4) = u;
  }
}

// ---------------- compact flash attention over selected q/k ----------------
__global__ __launch_bounds__(256) void k_attn(
    const unsigned short* __restrict__ qc, const unsigned short* __restrict__ kc,
    const unsigned short* __restrict__ vctr, unsigned short* __restrict__ vnew,
    const unsigned int* __restrict__ idx, const unsigned int* __restrict__ cnt) {
  __shared__ __align__(16) unsigned short k_lds[64 * 64];
  __shared__ __align__(16) unsigned short v_lds[64 * 64];
  __shared__ __align__(16) unsigned short p_lds[4][16 * 72];
  int qt = blockIdx.x, h = blockIdx.y, b = blockIdx.z;
  unsigned int nq = cnt[b], nk = cnt[B_ + b];
  if (qt * 64 >= (int)nq) return;                      // uniform exit
  int t = threadIdx.x, wave = t >> 6, lane = t & 63;
  int q0 = qt * 64 + wave * 16;
  const unsigned short* qp =
      qc + ((size_t)b * N_ + q0 + (lane & 15)) * C_ + h * HD_ + ((lane >> 4) * 8);
  bf16x8 qf0 = *(const bf16x8*)qp;
  bf16x8 qf1 = *(const bf16x8*)(qp + 32);
  float mrow[4], lrow[4];
  f32x4 acc[4];
#pragma unroll
  for (int r = 0; r < 4; r++) { mrow[r] = -1e30f; lrow[r] = 0.f; }
#pragma unroll
  for (int d = 0; d < 4; d++) acc[d] = f32x4{0.f, 0.f, 0.f, 0.f};
  int srow = t >> 3, spch = t & 7;
  int nkt = ((int)nk + 63) >> 6;
  for (int kt = 0; kt < nkt; kt++) {
    int n0 = kt * 64;
    __syncthreads();
#pragma unroll
    for (int i = 0; i < 2; i++) {
      int row = srow + i * 32;
      int lch = spch ^ (row & 7);
      gload16(kc + ((size_t)b * N_ + n0 + row) * C_ + h * HD_ + lch * 8,
              (char*)k_lds + wave * 1024 + i * 4096);
      gload16(vctr + ((size_t)b * C_ + h * HD_ + row) * N_ + n0 + lch * 8,
              (char*)v_lds + wave * 1024 + i * 4096);
    }
    __syncthreads();
    // S = (Q K^T) * scale + pad mask
    f32x4 s[4];
#pragma unroll
    for (int nf = 0; nf < 4; nf++) {
      int row = nf * 16 + (lane & 15);
      f32x4 z = {0.f, 0.f, 0.f, 0.f};
      {
        int pch = ((lane >> 4)) ^ (row & 7);
        bf16x8 kf = *(const bf16x8*)(k_lds + row * 64 + pch * 8);
        z = __builtin_amdgcn_mfma_f32_16x16x32_bf16(qf0, kf, z, 0, 0, 0);
      }
      {
        int pch = (4 + (lane >> 4)) ^ (row & 7);
        bf16x8 kf = *(const bf16x8*)(k_lds + row * 64 + pch * 8);
        z = __builtin_amdgcn_mfma_f32_16x16x32_bf16(qf1, kf, z, 0, 0, 0);
      }
      float mv = ((n0 + row) < (int)nk) ? 0.f : -1e30f;
#pragma unroll
      for (int r = 0; r < 4; r++) s[nf][r] = z[r] * 0.125f + mv;
    }
    // online softmax per q-row
    float alpha[4];
#pragma unroll
    for (int r = 0; r < 4; r++) {
      float mx = fmaxf(fmaxf(s[0][r], s[1][r]), fmaxf(s[2][r], s[3][r]));
      mx = fmaxf(mx, __shfl_xor(mx, 1));
      mx = fmaxf(mx, __shfl_xor(mx, 2));
      mx = fmaxf(mx, __shfl_xor(mx, 4));
      mx = fmaxf(mx, __shfl_xor(mx, 8));
      float mn = fmaxf(mrow[r], mx);
      alpha[r] = __expf(mrow[r] - mn);
      mrow[r] = mn;
      float rs = 0.f;
      int ql = ((lane >> 4) << 2) + r;
#pragma unroll
      for (int nf = 0; nf < 4; nf++) {
        float sv = s[nf][r];
        float p = (sv < -1e29f) ? 0.f : __expf(sv - mn);
        rs += p;
        p_lds[wave][ql * 72 + nf * 16 + (lane & 15)] = f2bf(p);
      }
      rs += __shfl_xor(rs, 1);
      rs += __shfl_xor(rs, 2);
      rs += __shfl_xor(rs, 4);
      rs += __shfl_xor(rs, 8);
      lrow[r] = lrow[r] * alpha[r] + rs;
    }
    // PV (wave-local P buffer; in-wave lgkmcnt ordering suffices)
    bf16x8 pa0 = *(const bf16x8*)&p_lds[wave][(lane & 15) * 72 + ((lane >> 4) * 8)];
    bf16x8 pa1 = *(const bf16x8*)&p_lds[wave][(lane & 15) * 72 + 32 + ((lane >> 4) * 8)];
#pragma unroll
    for (int df = 0; df < 4; df++) {
#pragma unroll
      for (int r = 0; r < 4; r++) acc[df][r] *= alpha[r];
      int row = df * 16 + (lane & 15);
      int pch0 = ((lane >> 4)) ^ (row & 7);
      int pch1 = (4 + (lane >> 4)) ^ (row & 7);
      bf16x8 vf0 = *(const bf16x8*)(v_lds + row * 64 + pch0 * 8);
      bf16x8 vf1 = *(const bf16x8*)(v_lds + row * 64 + pch1 * 8);
      acc[df] = __builtin_amdgcn_mfma_f32_16x16x32_bf16(pa0, vf0, acc[df], 0, 0, 0);
      acc[df] = __builtin_amdgcn_mfma_f32_16x16x32_bf16(pa1, vf1, acc[df], 0, 0, 0);
    }
  }
  // scatter output rows back into v_new at original positions
#pragma unroll
  for (int r = 0; r < 4; r++) {
    int ii = q0 + ((lane >> 4) << 2) + r;
    if (ii < (int)nq) {
      unsigned int qrow = idx[(size_t)b * N_ + ii];
      float inv = 1.0f / lrow[r];
      unsigned short* dst = vnew + ((size_t)b * N_ + qrow) * C_ + h * HD_ + (lane & 15);
#pragma unroll
      for (int df = 0; df < 4; df++) dst[df * 16] = f2bf(acc[df][r] * inv);
    }
  }
}

extern "C" void kernel_launch(void* const* d_in, const int* in_sizes, int n_in,
                              void* d_out, int out_size, void* d_ws, size_t ws_size,
                              hipStream_t stream) {
  const float* x   = (const float*)d_in[0];
  const float* u_q = (const float*)d_in[1];
  const float* u_k = (const float*)d_in[2];
  const float* wqs = (const float*)d_in[3];
  const float* bqs = (const float*)d_in[4];
  const float* wks = (const float*)d_in[5];
  const float* bks = (const float*)d_in[6];
  const float* Wq  = (const float*)d_in[7];
  const float* bq  = (const float*)d_in[8];
  const float* Wk  = (const float*)d_in[9];
  const float* bk  = (const float*)d_in[10];
  const float* Wv  = (const float*)d_in[11];
  const float* bv  = (const float*)d_in[12];
  const float* Wp  = (const float*)d_in[13];
  const float* bp  = (const float*)d_in[14];

  char* ws = (char*)d_ws;
  unsigned short* xT   = (unsigned short*)(ws);              // 8 MB
  unsigned short* wbf  = (unsigned short*)(ws + 8388608);    // 2 MB
  unsigned short* qkv  = (unsigned short*)(ws + 10485760);   // 3 x 8 MB (qc, kc, vT)
  unsigned short* qc   = qkv;
  unsigned short* kc   = qkv + (size_t)B_ * N_ * C_;
  unsigned short* vT   = kc + (size_t)B_ * N_ * C_;          // dense v; v_new in-place
  unsigned short* vctr = (unsigned short*)(ws + 35651584);   // 8 MB
  unsigned int*   sel  = (unsigned int*)(ws + 44040192);     // 64 KB [2][B][N]
  unsigned int*   idx  = (unsigned int*)(ws + 44105728);     // 64 KB [2][B][N]
  unsigned int*   cnt  = (unsigned int*)(ws + 44171264);     // 64 B  [2][B]

  k_convw<<<dim3(4096), 256, 0, stream>>>(Wq, Wk, Wv, Wp, wbf);
  k_transpose_x<<<dim3(16, 8, 8), 256, 0, stream>>>(x, xT);
  k_mask<<<dim3(32, 8), 256, 0, stream>>>(x, u_q, u_k, wqs, bqs, wks, bks, sel);
  k_scan<<<dim3(2, 8), 1024, 0, stream>>>(sel, idx, cnt);
  k_gemm<0><<<dim3(8, 4, 24), 256, 0, stream>>>(wbf, xT, bq, bk, bv, idx, cnt, (void*)qkv);
  k_gather_vt<<<dim3(16, 8, 8), 256, 0, stream>>>(vT, idx, cnt, vctr);
  k_attn<<<dim3(16, 8, 8), 256, 0, stream>>>(qc, kc, vctr, vT, idx, cnt);
  k_gemm<1><<<dim3(8, 4, 8), 256, 0, stream>>>(wbf + 3 * 262144, vT, bp, bp, bp, idx, cnt, d_out);
}

// Round 4
// 167.702 us; speedup vs baseline: 1.4940x; 1.0595x over previous
//
#include <hip/hip_runtime.h>
#include <hip/hip_bf16.h>

#define B_ 8
#define C_ 512
#define N_ 1024
#define HEADS_ 8
#define HD_ 64

using f32x4  = __attribute__((ext_vector_type(4))) float;
using bf16x8 = __attribute__((ext_vector_type(8))) __bf16;

__device__ __forceinline__ unsigned short f2bf(float f) {
  union { float f; unsigned u; } v; v.f = f;
  unsigned r = v.u + 0x7FFFu + ((v.u >> 16) & 1u);
  return (unsigned short)(r >> 16);
}

__device__ __forceinline__ void gload16(const void* g, void* l) {
  __builtin_amdgcn_global_load_lds(
      (const __attribute__((address_space(1))) unsigned int*)g,
      (__attribute__((address_space(3))) unsigned int*)l, 16, 0, 0);
}

// ---------------- weight f32->bf16 (vectorized x4) ----------------
__global__ __launch_bounds__(256) void k_convw(
    const float* __restrict__ wq, const float* __restrict__ wk,
    const float* __restrict__ wv, const float* __restrict__ wp,
    unsigned short* __restrict__ out) {
  int i = blockIdx.x * 256 + threadIdx.x;      // 0..262143 float4s
  int mat = i >> 16, idx4 = i & 65535;
  const float* src = (mat == 0) ? wq : (mat == 1) ? wk : (mat == 2) ? wv : wp;
  float4 v = ((const float4*)src)[idx4];
  unsigned lo = (unsigned)f2bf(v.x) | ((unsigned)f2bf(v.y) << 16);
  unsigned hi = (unsigned)f2bf(v.z) | ((unsigned)f2bf(v.w) << 16);
  uint2 u; u.x = lo; u.y = hi;
  ((uint2*)out)[i] = u;
}

// ---------------- x [b][c][n] f32 -> xT [b][n][c] bf16 ----------------
__global__ __launch_bounds__(256) void k_transpose_x(
    const float* __restrict__ x, unsigned short* __restrict__ xT) {
  __shared__ float tile[64][65];
  int n0 = blockIdx.x * 64, c0 = blockIdx.y * 64, b = blockIdx.z;
  int t = threadIdx.x, tr = t >> 2, tc = (t & 3) * 16;
  const float* src = x + ((size_t)b * C_ + c0) * N_ + n0;
#pragma unroll
  for (int i = 0; i < 4; i++) {
    float4 v4 = *(const float4*)(src + (size_t)tr * N_ + tc + i * 4);
    tile[tr][tc + i * 4 + 0] = v4.x; tile[tr][tc + i * 4 + 1] = v4.y;
    tile[tr][tc + i * 4 + 2] = v4.z; tile[tr][tc + i * 4 + 3] = v4.w;
  }
  __syncthreads();
  unsigned short* dst = xT + ((size_t)b * N_ + n0) * C_ + c0;
#pragma unroll
  for (int i = 0; i < 4; i++) {
    unsigned short o4[4];
#pragma unroll
    for (int j = 0; j < 4; j++) o4[j] = f2bf(tile[tc + i * 4 + j][tr]);
    unsigned lo = (unsigned)o4[0] | ((unsigned)o4[1] << 16);
    unsigned hi = (unsigned)o4[2] | ((unsigned)o4[3] << 16);
    uint2 u; u.x = lo; u.y = hi;
    *(uint2*)(dst + (size_t)tr * C_ + tc + i * 4) = u;
  }
}

// ---------------- gumbel argmax selection flags (f32; split-C parallel) ----------------
__global__ __launch_bounds__(256) void k_mask(
    const float* __restrict__ x, const float* __restrict__ u_q, const float* __restrict__ u_k,
    const float* __restrict__ wqs, const float* __restrict__ bqs,
    const float* __restrict__ wks, const float* __restrict__ bks,
    unsigned int* __restrict__ sel) {   // sel[0][b][n]=q, sel[1][b][n]=k
  __shared__ float wq_l[4][512];
  __shared__ float wk_l[4][512];
  __shared__ float part[8 * 32 * 9];   // [chunk][nl][8 partials], stride 9 pad
  int b = blockIdx.y;
  int n0 = blockIdx.x * 32;
  int t = threadIdx.x, nl = t & 31, ch = t >> 5;
  for (int i = t; i < 2048; i += 256) {
    wq_l[i >> 9][i & 511] = wqs[i];
    wk_l[i >> 9][i & 511] = wks[i];
  }
  __syncthreads();
  int cbase = ch * 64;
  const float* xp = x + ((size_t)b * C_ + cbase) * N_ + n0 + nl;
  float sq[4] = {0.f, 0.f, 0.f, 0.f};
  float sk[4] = {0.f, 0.f, 0.f, 0.f};
  for (int c = 0; c < 64; c++) {
    float xv = xp[(size_t)c * N_];
#pragma unroll
    for (int r = 0; r < 4; r++) {
      sq[r] = fmaf(wq_l[r][cbase + c], xv, sq[r]);
      sk[r] = fmaf(wk_l[r][cbase + c], xv, sk[r]);
    }
  }
  float* pp = part + (ch * 32 + nl) * 9;
#pragma unroll
  for (int r = 0; r < 4; r++) { pp[r] = sq[r]; pp[4 + r] = sk[r]; }
  __syncthreads();
  if (t < 32) {
    int n = n0 + t;
    float fq[4], fk[4];
#pragma unroll
    for (int r = 0; r < 4; r++) { fq[r] = bqs[r]; fk[r] = bks[r]; }
#pragma unroll
    for (int c2 = 0; c2 < 8; c2++) {
      const float* q2 = part + (c2 * 32 + t) * 9;
#pragma unroll
      for (int r = 0; r < 4; r++) { fq[r] += q2[r]; fk[r] += q2[4 + r]; }
    }
#pragma unroll
    for (int r = 0; r < 4; r++) {
      float uq = u_q[((size_t)b * 4 + r) * N_ + n];
      float uk = u_k[((size_t)b * 4 + r) * N_ + n];
      fq[r] += -logf(-logf(uq + 1e-10f) + 1e-10f);
      fk[r] += -logf(-logf(uk + 1e-10f) + 1e-10f);
    }
    bool selq = (fq[0] >= fq[1]) && (fq[0] >= fq[2]) && (fq[0] >= fq[3]);
    bool selk = (fk[0] >= fk[1]) && (fk[0] >= fk[2]) && (fk[0] >= fk[3]);
    sel[(size_t)b * N_ + n] = selq ? 1u : 0u;
    sel[(size_t)(B_ + b) * N_ + n] = selk ? 1u : 0u;
  }
}

// ---------------- compaction scan: flags -> index lists + counts ----------------
__global__ __launch_bounds__(1024) void k_scan(
    const unsigned int* __restrict__ sel, unsigned int* __restrict__ idx,
    unsigned int* __restrict__ cnt) {
  int which = blockIdx.x, b = blockIdx.y;
  const unsigned int* s = sel + ((size_t)which * B_ + b) * N_;
  unsigned int* ip = idx + ((size_t)which * B_ + b) * N_;
  int t = threadIdx.x, lane = t & 63, w = t >> 6;   // 16 waves
  __shared__ unsigned int wtot[16], woff[16], totsh;
  unsigned int f = s[t];
  unsigned long long bal = __ballot(f != 0);
  unsigned int wpre = __popcll(bal & ((1ull << lane) - 1ull));
  if (lane == 0) wtot[w] = (unsigned int)__popcll(bal);
  __syncthreads();
  if (t == 0) {
    unsigned int acc = 0;
#pragma unroll
    for (int i = 0; i < 16; i++) { woff[i] = acc; acc += wtot[i]; }
    totsh = acc;
    cnt[which * B_ + b] = acc;
  }
  __syncthreads();
  unsigned int tot = totsh;
  if (f) ip[woff[w] + wpre] = (unsigned int)t;
  if (t >= (int)tot) ip[t] = 0u;   // safe pad rows (disjoint range)
}

// ---------------- BT-form bf16 MFMA GEMM, 128x128 tile, BK=64, 2-phase dbuf ----------------
// MODE 0: mat 0=q (gathered rows via idx[0], compact out), 1=k (idx[1]), 2=v dense.
//         out bf16 [mat][b][row][o].
// MODE 1: dense, out f32 [b][o][n].
template <int MODE>
__global__ __launch_bounds__(256) void k_gemm(
    const unsigned short* __restrict__ Wall, const unsigned short* __restrict__ Bt,
    const float* __restrict__ bias0, const float* __restrict__ bias1,
    const float* __restrict__ bias2,
    const unsigned int* __restrict__ idx, const unsigned int* __restrict__ cnt,
    void* __restrict__ outv) {
  __shared__ __align__(16) unsigned short a_lds[2][128 * 64];
  __shared__ __align__(16) unsigned short b_lds[2][128 * 64];
  int z = blockIdx.z;
  int mat = (MODE == 0) ? (z >> 3) : 0;
  int b   = (MODE == 0) ? (z & 7) : z;
  int n0 = blockIdx.x * 128;
  if (MODE == 0 && mat < 2 && n0 >= (int)cnt[mat * B_ + b]) return;  // uniform exit
  const unsigned short* A = Wall + (size_t)mat * 262144;
  const float* bias = (mat == 0) ? bias0 : (mat == 1) ? bias1 : bias2;
  int m0 = blockIdx.y * 128;
  int t = threadIdx.x, wave = t >> 6, lane = t & 63;
  int wr = (wave >> 1) * 64, wc = (wave & 1) * 64;
  f32x4 acc[4][4] = {};
  int srow = t >> 3, spch = t & 7;
  int lch = spch ^ (srow & 7);               // pre-swizzled global source, linear LDS dest
  const unsigned short* aptr[4];
  const unsigned short* bptr[4];
#pragma unroll
  for (int i = 0; i < 4; i++) {
    int row = srow + i * 32;
    aptr[i] = A + (size_t)(m0 + row) * C_ + lch * 8;
    int grow = n0 + row;
    int srcr = (MODE == 0 && mat < 2) ? (int)idx[((size_t)mat * B_ + b) * N_ + grow] : grow;
    bptr[i] = Bt + ((size_t)b * N_ + srcr) * C_ + lch * 8;
  }
#define STAGE_(buf, kt) do { int k0_ = (kt) * 64;                                   \
    _Pragma("unroll") for (int i_ = 0; i_ < 4; i_++) {                              \
      gload16(aptr[i_] + k0_, (char*)a_lds + (buf) * 16384 + wave * 1024 + i_ * 4096); \
      gload16(bptr[i_] + k0_, (char*)b_lds + (buf) * 16384 + wave * 1024 + i_ * 4096); \
    } } while (0)
  STAGE_(0, 0);
  for (int kt = 0; kt < 8; kt++) {
    int cur = kt & 1;
    if (kt < 7) {
      STAGE_(cur ^ 1, kt + 1);
      asm volatile("s_waitcnt vmcnt(8)" ::: "memory");   // current tile landed; next in flight
    } else {
      asm volatile("s_waitcnt vmcnt(0)" ::: "memory");
    }
    __builtin_amdgcn_s_barrier();                        // raw: no vmcnt(0) drain
    const unsigned short* al = a_lds[cur];
    const unsigned short* bl = b_lds[cur];
#pragma unroll
    for (int ks = 0; ks < 2; ks++) {
      bf16x8 af[4], bfr[4];
#pragma unroll
      for (int mi = 0; mi < 4; mi++) {
        int row = wr + mi * 16 + (lane & 15);
        int pch = (ks * 4 + (lane >> 4)) ^ (row & 7);
        af[mi] = *(const bf16x8*)(al + row * 64 + pch * 8);
      }
#pragma unroll
      for (int ni = 0; ni < 4; ni++) {
        int row = wc + ni * 16 + (lane & 15);
        int pch = (ks * 4 + (lane >> 4)) ^ (row & 7);
        bfr[ni] = *(const bf16x8*)(bl + row * 64 + pch * 8);
      }
#pragma unroll
      for (int mi = 0; mi < 4; mi++)
#pragma unroll
        for (int ni = 0; ni < 4; ni++)
          acc[mi][ni] = __builtin_amdgcn_mfma_f32_16x16x32_bf16(af[mi], bfr[ni], acc[mi][ni], 0, 0, 0);
    }
    __builtin_amdgcn_s_barrier();                        // reads done before next overwrite
  }
#undef STAGE_
  if (MODE == 0) {
    unsigned short* outp = (unsigned short*)outv + (size_t)mat * B_ * N_ * C_ + (size_t)b * N_ * C_;
#pragma unroll
    for (int mi = 0; mi < 4; mi++) {
      int ob = m0 + wr + mi * 16 + ((lane >> 4) << 2);
      float bs[4];
#pragma unroll
      for (int r = 0; r < 4; r++) bs[r] = bias[ob + r];
#pragma unroll
      for (int ni = 0; ni < 4; ni++) {
        int n = n0 + wc + ni * 16 + (lane & 15);
        unsigned short o4[4];
#pragma unroll
        for (int r = 0; r < 4; r++) o4[r] = f2bf(acc[mi][ni][r] + bs[r]);
        unsigned lo = (unsigned)o4[0] | ((unsigned)o4[1] << 16);
        unsigned hi = (unsigned)o4[2] | ((unsigned)o4[3] << 16);
        uint2 u; u.x = lo; u.y = hi;
        *(uint2*)(outp + (size_t)n * C_ + ob) = u;
      }
    }
  } else {
    float* outp = (float*)outv + (size_t)b * C_ * N_;
#pragma unroll
    for (int mi = 0; mi < 4; mi++) {
      int ob = m0 + wr + mi * 16 + ((lane >> 4) << 2);
#pragma unroll
      for (int r = 0; r < 4; r++) {
        float bv = bias[ob + r];
#pragma unroll
        for (int ni = 0; ni < 4; ni++) {
          int n = n0 + wc + ni * 16 + (lane & 15);
          outp[(size_t)(ob + r) * N_ + n] = acc[mi][ni][r] + bv;
        }
      }
    }
  }
}

// ---------------- gather+transpose: vctr[b][c][jj] = vT[b][kidx[jj]][c] ----------------
__global__ __launch_bounds__(256) void k_gather_vt(
    const unsigned short* __restrict__ vT, const unsigned int* __restrict__ idx,
    const unsigned int* __restrict__ cnt, unsigned short* __restrict__ vctr) {
  int b = blockIdx.z;
  unsigned int nk = cnt[B_ + b];
  int j0 = blockIdx.x * 64;
  if (j0 >= (int)nk) return;
  int c0 = blockIdx.y * 64;
  __shared__ unsigned short tile[64][72];
  int t = threadIdx.x, tr = t >> 2, tc = (t & 3) * 16;
  int jj = j0 + tr;
  bool valid = jj < (int)nk;
  unsigned int srow = valid ? idx[((size_t)B_ + b) * N_ + jj] : 0u;
  const unsigned short* src = vT + ((size_t)b * N_ + srow) * C_ + c0;
#pragma unroll
  for (int i = 0; i < 4; i++) {
    ushort4 v4 = {0, 0, 0, 0};
    if (valid) v4 = *(const ushort4*)(src + tc + i * 4);
    tile[tr][tc + i * 4 + 0] = v4.x; tile[tr][tc + i * 4 + 1] = v4.y;
    tile[tr][tc + i * 4 + 2] = v4.z; tile[tr][tc + i * 4 + 3] = v4.w;
  }
  __syncthreads();
  unsigned short* dst = vctr + ((size_t)b * C_ + c0) * N_ + j0;
#pragma unroll
  for (int i = 0; i < 4; i++) {
    unsigned short o4[4];
#pragma unroll
    for (int j = 0; j < 4; j++) o4[j] = tile[tc + i * 4 + j][tr];
    unsigned lo = (unsigned)o4[0] | ((unsigned)o4[1] << 16);
    unsigned hi = (unsigned)o4[2] | ((unsigned)o4[3] << 16);
    uint2 u; u.x = lo; u.y = hi;
    *(uint2*)(dst + (size_t)tr * N_ + tc + i * 4) = u;
  }
}

// ---------------- compact flash attention: 16-q strips, 4 waves split keys, LDS merge ----------------
__global__ __launch_bounds__(256) void k_attn(
    const unsigned short* __restrict__ qc, const unsigned short* __restrict__ kc,
    const unsigned short* __restrict__ vctr, unsigned short* __restrict__ vnew,
    const unsigned int* __restrict__ idx, const unsigned int* __restrict__ cnt) {
  __shared__ __align__(16) unsigned short p_lds[4][16 * 72];
  __shared__ float macc[4][16][65];
  __shared__ float mml[4][2][16];
  int qt = blockIdx.x, h = blockIdx.y, b = blockIdx.z;
  int nq = (int)cnt[b], nk = (int)cnt[B_ + b];
  int q0 = qt * 16;
  if (q0 >= nq) return;                                  // uniform exit
  int t = threadIdx.x, wave = t >> 6, lane = t & 63;
  const unsigned short* qp =
      qc + ((size_t)b * N_ + q0 + (lane & 15)) * C_ + h * HD_ + ((lane >> 4) * 8);
  bf16x8 qf0 = *(const bf16x8*)qp;
  bf16x8 qf1 = *(const bf16x8*)(qp + 32);
  float mrow[4], lrow[4];
  f32x4 acc[4];
#pragma unroll
  for (int r = 0; r < 4; r++) { mrow[r] = -1e30f; lrow[r] = 0.f; }
#pragma unroll
  for (int d = 0; d < 4; d++) acc[d] = f32x4{0.f, 0.f, 0.f, 0.f};
  // wave-private key chunks: no barriers, no K/V LDS — direct global->VGPR (L2-hot)
  for (int j0 = wave * 64; j0 < nk; j0 += 256) {
    f32x4 s[4];
#pragma unroll
    for (int nf = 0; nf < 4; nf++) {
      const unsigned short* kp =
          kc + ((size_t)b * N_ + j0 + nf * 16 + (lane & 15)) * C_ + h * HD_ + ((lane >> 4) * 8);
      bf16x8 kf0 = *(const bf16x8*)kp;
      bf16x8 kf1 = *(const bf16x8*)(kp + 32);
      f32x4 z = {0.f, 0.f, 0.f, 0.f};
      z = __builtin_amdgcn_mfma_f32_16x16x32_bf16(qf0, kf0, z, 0, 0, 0);
      z = __builtin_amdgcn_mfma_f32_16x16x32_bf16(qf1, kf1, z, 0, 0, 0);
      float mv = ((j0 + nf * 16 + (lane & 15)) < nk) ? 0.f : -1e30f;
#pragma unroll
      for (int r = 0; r < 4; r++) s[nf][r] = z[r] * 0.125f + mv;
    }
    float alpha[4];
#pragma unroll
    for (int r = 0; r < 4; r++) {
      float mx = fmaxf(fmaxf(s[0][r], s[1][r]), fmaxf(s[2][r], s[3][r]));
      mx = fmaxf(mx, __shfl_xor(mx, 1));
      mx = fmaxf(mx, __shfl_xor(mx, 2));
      mx = fmaxf(mx, __shfl_xor(mx, 4));
      mx = fmaxf(mx, __shfl_xor(mx, 8));
      float mn = fmaxf(mrow[r], mx);
      alpha[r] = __expf(mrow[r] - mn);
      mrow[r] = mn;
      float rs = 0.f;
      int ql = ((lane >> 4) << 2) + r;
#pragma unroll
      for (int nf = 0; nf < 4; nf++) {
        float sv = s[nf][r];
        float p = (sv < -1e29f) ? 0.f : __expf(sv - mn);
        rs += p;
        p_lds[wave][ql * 72 + nf * 16 + (lane & 15)] = f2bf(p);
      }
      rs += __shfl_xor(rs, 1);
      rs += __shfl_xor(rs, 2);
      rs += __shfl_xor(rs, 4);
      rs += __shfl_xor(rs, 8);
      lrow[r] = lrow[r] * alpha[r] + rs;
    }
    bf16x8 pa0 = *(const bf16x8*)&p_lds[wave][(lane & 15) * 72 + ((lane >> 4) * 8)];
    bf16x8 pa1 = *(const bf16x8*)&p_lds[wave][(lane & 15) * 72 + 32 + ((lane >> 4) * 8)];
#pragma unroll
    for (int df = 0; df < 4; df++) {
#pragma unroll
      for (int r = 0; r < 4; r++) acc[df][r] *= alpha[r];
      const unsigned short* vp =
          vctr + ((size_t)b * C_ + h * HD_ + df * 16 + (lane & 15)) * N_ + j0 + ((lane >> 4) * 8);
      bf16x8 vf0 = *(const bf16x8*)vp;
      bf16x8 vf1 = *(const bf16x8*)(vp + 32);
      acc[df] = __builtin_amdgcn_mfma_f32_16x16x32_bf16(pa0, vf0, acc[df], 0, 0, 0);
      acc[df] = __builtin_amdgcn_mfma_f32_16x16x32_bf16(pa1, vf1, acc[df], 0, 0, 0);
    }
  }
  // deposit per-wave partial state
#pragma unroll
  for (int df = 0; df < 4; df++)
#pragma unroll
    for (int r = 0; r < 4; r++)
      macc[wave][((lane >> 4) << 2) + r][df * 16 + (lane & 15)] = acc[df][r];
  if ((lane & 15) == 0) {
#pragma unroll
    for (int r = 0; r < 4; r++) {
      mml[wave][0][((lane >> 4) << 2) + r] = mrow[r];
      mml[wave][1][((lane >> 4) << 2) + r] = lrow[r];
    }
  }
  __syncthreads();
  // merge 4 wave-partials: thread t -> q = t>>4, d0 = (t&15)*4
  {
    int q = t >> 4, d0 = (t & 15) * 4;
    float mg = fmaxf(fmaxf(mml[0][0][q], mml[1][0][q]), fmaxf(mml[2][0][q], mml[3][0][q]));
    float lg = 0.f, o0 = 0.f, o1 = 0.f, o2 = 0.f, o3 = 0.f;
#pragma unroll
    for (int w = 0; w < 4; w++) {
      float sc = __expf(mml[w][0][q] - mg);
      lg += mml[w][1][q] * sc;
      o0 += macc[w][q][d0 + 0] * sc;
      o1 += macc[w][q][d0 + 1] * sc;
      o2 += macc[w][q][d0 + 2] * sc;
      o3 += macc[w][q][d0 + 3] * sc;
    }
    if (q0 + q < nq) {
      unsigned int qrow = idx[(size_t)b * N_ + q0 + q];
      float inv = 1.0f / lg;
      unsigned short o4[4] = {f2bf(o0 * inv), f2bf(o1 * inv), f2bf(o2 * inv), f2bf(o3 * inv)};
      unsigned lo = (unsigned)o4[0] | ((unsigned)o4[1] << 16);
      unsigned hi = (unsigned)o4[2] | ((unsigned)o4[3] << 16);
      uint2 u; u.x = lo; u.y = hi;
      *(uint2*)(vnew + ((size_t)b * N_ + qrow) * C_ + h * HD_ + d0) = u;
    }
  }
}

extern "C" void kernel_launch(void* const* d_in, const int* in_sizes, int n_in,
                              void* d_out, int out_size, void* d_ws, size_t ws_size,
                              hipStream_t stream) {
  const float* x   = (const float*)d_in[0];
  const float* u_q = (const float*)d_in[1];
  const float* u_k = (const float*)d_in[2];
  const float* wqs = (const float*)d_in[3];
  const float* bqs = (const float*)d_in[4];
  const float* wks = (const float*)d_in[5];
  const float* bks = (const float*)d_in[6];
  const float* Wq  = (const float*)d_in[7];
  const float* bq  = (const float*)d_in[8];
  const float* Wk  = (const float*)d_in[9];
  const float* bk  = (const float*)d_in[10];
  const float* Wv  = (const float*)d_in[11];
  const float* bv  = (const float*)d_in[12];
  const float* Wp  = (const float*)d_in[13];
  const float* bp  = (const float*)d_in[14];

  char* ws = (char*)d_ws;
  unsigned short* xT   = (unsigned short*)(ws);              // 8 MB
  unsigned short* wbf  = (unsigned short*)(ws + 8388608);    // 2 MB
  unsigned short* qkv  = (unsigned short*)(ws + 10485760);   // 3 x 8 MB (qc, kc, vT)
  unsigned short* qc   = qkv;
  unsigned short* kc   = qkv + (size_t)B_ * N_ * C_;
  unsigned short* vT   = kc + (size_t)B_ * N_ * C_;          // dense v; v_new in-place
  unsigned short* vctr = (unsigned short*)(ws + 35651584);   // 8 MB
  unsigned int*   sel  = (unsigned int*)(ws + 44040192);     // 64 KB [2][B][N]
  unsigned int*   idx  = (unsigned int*)(ws + 44105728);     // 64 KB [2][B][N]
  unsigned int*   cnt  = (unsigned int*)(ws + 44171264);     // 64 B  [2][B]

  k_convw<<<dim3(1024), 256, 0, stream>>>(Wq, Wk, Wv, Wp, wbf);
  k_transpose_x<<<dim3(16, 8, 8), 256, 0, stream>>>(x, xT);
  k_mask<<<dim3(32, 8), 256, 0, stream>>>(x, u_q, u_k, wqs, bqs, wks, bks, sel);
  k_scan<<<dim3(2, 8), 1024, 0, stream>>>(sel, idx, cnt);
  k_gemm<0><<<dim3(8, 4, 24), 256, 0, stream>>>(wbf, xT, bq, bk, bv, idx, cnt, (void*)qkv);
  k_gather_vt<<<dim3(16, 8, 8), 256, 0, stream>>>(vT, idx, cnt, vctr);
  k_attn<<<dim3(64, 8, 8), 256, 0, stream>>>(qc, kc, vctr, vT, idx, cnt);
  k_gemm<1><<<dim3(8, 4, 8), 256, 0, stream>>>(wbf + 3 * 262144, vT, bp, bp, bp, idx, cnt, d_out);
}

// Round 5
// 164.544 us; speedup vs baseline: 1.5227x; 1.0192x over previous
//
#include <hip/hip_runtime.h>
#include <hip/hip_bf16.h>

#define B_ 8
#define C_ 512
#define N_ 1024
#define HEADS_ 8
#define HD_ 64

using f32x4  = __attribute__((ext_vector_type(4))) float;
using bf16x8 = __attribute__((ext_vector_type(8))) __bf16;

__device__ __forceinline__ unsigned short f2bf(float f) {
  union { float f; unsigned u; } v; v.f = f;
  unsigned r = v.u + 0x7FFFu + ((v.u >> 16) & 1u);
  return (unsigned short)(r >> 16);
}

__device__ __forceinline__ void gload16(const void* g, void* l) {
  __builtin_amdgcn_global_load_lds(
      (const __attribute__((address_space(1))) unsigned int*)g,
      (__attribute__((address_space(3))) unsigned int*)l, 16, 0, 0);
}

// ---------------- fused prep: mask (blocks 0..255) | transpose_x (256..1279) | convw (1280..2303) ----------------
__global__ __launch_bounds__(256) void k_prep(
    const float* __restrict__ x, const float* __restrict__ u_q, const float* __restrict__ u_k,
    const float* __restrict__ wqs, const float* __restrict__ bqs,
    const float* __restrict__ wks, const float* __restrict__ bks,
    const float* __restrict__ Wq, const float* __restrict__ Wk,
    const float* __restrict__ Wv, const float* __restrict__ Wp,
    unsigned short* __restrict__ xT, unsigned short* __restrict__ wbf,
    unsigned int* __restrict__ sel) {
  __shared__ __align__(16) char smem[25600];
  int id = blockIdx.x;
  int t = threadIdx.x;
  if (id < 256) {
    // ---- gumbel argmax selection flags (f32; split-C; arithmetic identical to R3/R4) ----
    float* wq_l = (float*)smem;          // [4][512]
    float* wk_l = wq_l + 2048;           // [4][512]
    float* part = wk_l + 2048;           // [8*32*9]
    int b = id >> 5;
    int n0 = (id & 31) * 32;
    int nl = t & 31, ch = t >> 5;
    for (int i = t; i < 2048; i += 256) {
      wq_l[i] = wqs[i];
      wk_l[i] = wks[i];
    }
    __syncthreads();
    int cbase = ch * 64;
    const float* xp = x + ((size_t)b * C_ + cbase) * N_ + n0 + nl;
    float sq[4] = {0.f, 0.f, 0.f, 0.f};
    float sk[4] = {0.f, 0.f, 0.f, 0.f};
    for (int c = 0; c < 64; c++) {
      float xv = xp[(size_t)c * N_];
#pragma unroll
      for (int r = 0; r < 4; r++) {
        sq[r] = fmaf(wq_l[r * 512 + cbase + c], xv, sq[r]);
        sk[r] = fmaf(wk_l[r * 512 + cbase + c], xv, sk[r]);
      }
    }
    float* pp = part + (ch * 32 + nl) * 9;
#pragma unroll
    for (int r = 0; r < 4; r++) { pp[r] = sq[r]; pp[4 + r] = sk[r]; }
    __syncthreads();
    if (t < 32) {
      int n = n0 + t;
      float fq[4], fk[4];
#pragma unroll
      for (int r = 0; r < 4; r++) { fq[r] = bqs[r]; fk[r] = bks[r]; }
#pragma unroll
      for (int c2 = 0; c2 < 8; c2++) {
        const float* q2 = part + (c2 * 32 + t) * 9;
#pragma unroll
        for (int r = 0; r < 4; r++) { fq[r] += q2[r]; fk[r] += q2[4 + r]; }
      }
#pragma unroll
      for (int r = 0; r < 4; r++) {
        float uq = u_q[((size_t)b * 4 + r) * N_ + n];
        float uk = u_k[((size_t)b * 4 + r) * N_ + n];
        fq[r] += -logf(-logf(uq + 1e-10f) + 1e-10f);
        fk[r] += -logf(-logf(uk + 1e-10f) + 1e-10f);
      }
      bool selq = (fq[0] >= fq[1]) && (fq[0] >= fq[2]) && (fq[0] >= fq[3]);
      bool selk = (fk[0] >= fk[1]) && (fk[0] >= fk[2]) && (fk[0] >= fk[3]);
      sel[(size_t)b * N_ + n] = selq ? 1u : 0u;
      sel[(size_t)(B_ + b) * N_ + n] = selk ? 1u : 0u;
    }
  } else if (id < 1280) {
    // ---- x [b][c][n] f32 -> xT [b][n][c] bf16 ----
    float (*tile)[65] = (float(*)[65])smem;
    int m = id - 256;
    int n0 = (m & 15) * 64, c0 = ((m >> 4) & 7) * 64, b = m >> 7;
    int tr = t >> 2, tc = (t & 3) * 16;
    const float* src = x + ((size_t)b * C_ + c0) * N_ + n0;
#pragma unroll
    for (int i = 0; i < 4; i++) {
      float4 v4 = *(const float4*)(src + (size_t)tr * N_ + tc + i * 4);
      tile[tr][tc + i * 4 + 0] = v4.x; tile[tr][tc + i * 4 + 1] = v4.y;
      tile[tr][tc + i * 4 + 2] = v4.z; tile[tr][tc + i * 4 + 3] = v4.w;
    }
    __syncthreads();
    unsigned short* dst = xT + ((size_t)b * N_ + n0) * C_ + c0;
#pragma unroll
    for (int i = 0; i < 4; i++) {
      unsigned short o4[4];
#pragma unroll
      for (int j = 0; j < 4; j++) o4[j] = f2bf(tile[tc + i * 4 + j][tr]);
      unsigned lo = (unsigned)o4[0] | ((unsigned)o4[1] << 16);
      unsigned hi = (unsigned)o4[2] | ((unsigned)o4[3] << 16);
      uint2 u; u.x = lo; u.y = hi;
      *(uint2*)(dst + (size_t)tr * C_ + tc + i * 4) = u;
    }
  } else {
    // ---- weights f32->bf16 (x4 vectorized) ----
    int i = (id - 1280) * 256 + t;       // 0..262143 float4s
    int mat = i >> 16, idx4 = i & 65535;
    const float* src = (mat == 0) ? Wq : (mat == 1) ? Wk : (mat == 2) ? Wv : Wp;
    float4 v = ((const float4*)src)[idx4];
    unsigned lo = (unsigned)f2bf(v.x) | ((unsigned)f2bf(v.y) << 16);
    unsigned hi = (unsigned)f2bf(v.z) | ((unsigned)f2bf(v.w) << 16);
    uint2 u; u.x = lo; u.y = hi;
    ((uint2*)wbf)[i] = u;
  }
}

// ---------------- compaction scan: flags -> index lists + counts ----------------
__global__ __launch_bounds__(1024) void k_scan(
    const unsigned int* __restrict__ sel, unsigned int* __restrict__ idx,
    unsigned int* __restrict__ cnt) {
  int which = blockIdx.x, b = blockIdx.y;
  const unsigned int* s = sel + ((size_t)which * B_ + b) * N_;
  unsigned int* ip = idx + ((size_t)which * B_ + b) * N_;
  int t = threadIdx.x, lane = t & 63, w = t >> 6;   // 16 waves
  __shared__ unsigned int wtot[16], woff[16], totsh;
  unsigned int f = s[t];
  unsigned long long bal = __ballot(f != 0);
  unsigned int wpre = __popcll(bal & ((1ull << lane) - 1ull));
  if (lane == 0) wtot[w] = (unsigned int)__popcll(bal);
  __syncthreads();
  if (t == 0) {
    unsigned int acc = 0;
#pragma unroll
    for (int i = 0; i < 16; i++) { woff[i] = acc; acc += wtot[i]; }
    totsh = acc;
    cnt[which * B_ + b] = acc;
  }
  __syncthreads();
  unsigned int tot = totsh;
  if (f) ip[woff[w] + wpre] = (unsigned int)t;
  if (t >= (int)tot) ip[t] = 0u;   // safe pad rows (disjoint range)
}

// ---------------- BT-form bf16 MFMA GEMM, 128x64 tile, BK=64, 2-phase dbuf ----------------
// 4 waves as 2x2 (wave-tile 64x32), 3 blocks/CU. MODE 0: mats q(idx),k(idx),v dense ->
// bf16 [mat][b][row][o]. MODE 1: dense -> f32 [b][o][n].
template <int MODE>
__global__ __launch_bounds__(256) void k_gemm(
    const unsigned short* __restrict__ Wall, const unsigned short* __restrict__ Bt,
    const float* __restrict__ bias0, const float* __restrict__ bias1,
    const float* __restrict__ bias2,
    const unsigned int* __restrict__ idx, const unsigned int* __restrict__ cnt,
    void* __restrict__ outv) {
  __shared__ __align__(16) unsigned short a_lds[2][128 * 64];
  __shared__ __align__(16) unsigned short b_lds[2][64 * 64];
  int z = blockIdx.z;
  int mat = (MODE == 0) ? (z >> 3) : 0;
  int b   = (MODE == 0) ? (z & 7) : z;
  int n0 = blockIdx.x * 64;
  if (MODE == 0 && mat < 2 && n0 >= (int)cnt[mat * B_ + b]) return;  // uniform exit
  const unsigned short* A = Wall + (size_t)mat * 262144;
  const float* bias = (mat == 0) ? bias0 : (mat == 1) ? bias1 : bias2;
  int m0 = blockIdx.y * 128;
  int t = threadIdx.x, wave = t >> 6, lane = t & 63;
  int wr = (wave >> 1) * 64, wc = (wave & 1) * 32;
  f32x4 acc[4][2] = {};
  int srow = t >> 3, spch = t & 7;
  int lch = spch ^ (srow & 7);               // pre-swizzled global source, linear LDS dest
  const unsigned short* aptr[4];
  const unsigned short* bptr[2];
#pragma unroll
  for (int i = 0; i < 4; i++)
    aptr[i] = A + (size_t)(m0 + srow + i * 32) * C_ + lch * 8;
#pragma unroll
  for (int i = 0; i < 2; i++) {
    int grow = n0 + srow + i * 32;
    int srcr = (MODE == 0 && mat < 2) ? (int)idx[((size_t)mat * B_ + b) * N_ + grow] : grow;
    bptr[i] = Bt + ((size_t)b * N_ + srcr) * C_ + lch * 8;
  }
#define STAGE_(buf, kt) do { int k0_ = (kt) * 64;                                          \
    _Pragma("unroll") for (int i_ = 0; i_ < 4; i_++)                                       \
      gload16(aptr[i_] + k0_, (char*)a_lds + (buf) * 16384 + wave * 1024 + i_ * 4096);     \
    _Pragma("unroll") for (int i_ = 0; i_ < 2; i_++)                                       \
      gload16(bptr[i_] + k0_, (char*)b_lds + (buf) * 8192 + wave * 1024 + i_ * 4096);      \
    } while (0)
  STAGE_(0, 0);
  for (int kt = 0; kt < 8; kt++) {
    int cur = kt & 1;
    if (kt < 7) {
      STAGE_(cur ^ 1, kt + 1);
      asm volatile("s_waitcnt vmcnt(6)" ::: "memory");   // current tile landed; next in flight
    } else {
      asm volatile("s_waitcnt vmcnt(0)" ::: "memory");
    }
    __builtin_amdgcn_s_barrier();                        // raw: no vmcnt(0) drain
    const unsigned short* al = a_lds[cur];
    const unsigned short* bl = b_lds[cur];
#pragma unroll
    for (int ks = 0; ks < 2; ks++) {
      bf16x8 af[4], bfr[2];
#pragma unroll
      for (int mi = 0; mi < 4; mi++) {
        int row = wr + mi * 16 + (lane & 15);
        int pch = (ks * 4 + (lane >> 4)) ^ (row & 7);
        af[mi] = *(const bf16x8*)(al + row * 64 + pch * 8);
      }
#pragma unroll
      for (int ni = 0; ni < 2; ni++) {
        int row = wc + ni * 16 + (lane & 15);
        int pch = (ks * 4 + (lane >> 4)) ^ (row & 7);
        bfr[ni] = *(const bf16x8*)(bl + row * 64 + pch * 8);
      }
#pragma unroll
      for (int mi = 0; mi < 4; mi++)
#pragma unroll
        for (int ni = 0; ni < 2; ni++)
          acc[mi][ni] = __builtin_amdgcn_mfma_f32_16x16x32_bf16(af[mi], bfr[ni], acc[mi][ni], 0, 0, 0);
    }
    __builtin_amdgcn_s_barrier();                        // reads done before next overwrite
  }
#undef STAGE_
  if (MODE == 0) {
    unsigned short* outp = (unsigned short*)outv + (size_t)mat * B_ * N_ * C_ + (size_t)b * N_ * C_;
#pragma unroll
    for (int mi = 0; mi < 4; mi++) {
      int ob = m0 + wr + mi * 16 + ((lane >> 4) << 2);
      float bs[4];
#pragma unroll
      for (int r = 0; r < 4; r++) bs[r] = bias[ob + r];
#pragma unroll
      for (int ni = 0; ni < 2; ni++) {
        int n = n0 + wc + ni * 16 + (lane & 15);
        unsigned short o4[4];
#pragma unroll
        for (int r = 0; r < 4; r++) o4[r] = f2bf(acc[mi][ni][r] + bs[r]);
        unsigned lo = (unsigned)o4[0] | ((unsigned)o4[1] << 16);
        unsigned hi = (unsigned)o4[2] | ((unsigned)o4[3] << 16);
        uint2 u; u.x = lo; u.y = hi;
        *(uint2*)(outp + (size_t)n * C_ + ob) = u;
      }
    }
  } else {
    float* outp = (float*)outv + (size_t)b * C_ * N_;
#pragma unroll
    for (int mi = 0; mi < 4; mi++) {
      int ob = m0 + wr + mi * 16 + ((lane >> 4) << 2);
#pragma unroll
      for (int r = 0; r < 4; r++) {
        float bv = bias[ob + r];
#pragma unroll
        for (int ni = 0; ni < 2; ni++) {
          int n = n0 + wc + ni * 16 + (lane & 15);
          outp[(size_t)(ob + r) * N_ + n] = acc[mi][ni][r] + bv;
        }
      }
    }
  }
}

// ---------------- gather+transpose: vctr[b][c][jj] = vT[b][kidx[jj]][c] ----------------
__global__ __launch_bounds__(256) void k_gather_vt(
    const unsigned short* __restrict__ vT, const unsigned int* __restrict__ idx,
    const unsigned int* __restrict__ cnt, unsigned short* __restrict__ vctr) {
  int b = blockIdx.z;
  unsigned int nk = cnt[B_ + b];
  int j0 = blockIdx.x * 64;
  if (j0 >= (int)nk) return;
  int c0 = blockIdx.y * 64;
  __shared__ unsigned short tile[64][72];
  int t = threadIdx.x, tr = t >> 2, tc = (t & 3) * 16;
  int jj = j0 + tr;
  bool valid = jj < (int)nk;
  unsigned int srow = valid ? idx[((size_t)B_ + b) * N_ + jj] : 0u;
  const unsigned short* src = vT + ((size_t)b * N_ + srow) * C_ + c0;
#pragma unroll
  for (int i = 0; i < 4; i++) {
    ushort4 v4 = {0, 0, 0, 0};
    if (valid) v4 = *(const ushort4*)(src + tc + i * 4);
    tile[tr][tc + i * 4 + 0] = v4.x; tile[tr][tc + i * 4 + 1] = v4.y;
    tile[tr][tc + i * 4 + 2] = v4.z; tile[tr][tc + i * 4 + 3] = v4.w;
  }
  __syncthreads();
  unsigned short* dst = vctr + ((size_t)b * C_ + c0) * N_ + j0;
#pragma unroll
  for (int i = 0; i < 4; i++) {
    unsigned short o4[4];
#pragma unroll
    for (int j = 0; j < 4; j++) o4[j] = tile[tc + i * 4 + j][tr];
    unsigned lo = (unsigned)o4[0] | ((unsigned)o4[1] << 16);
    unsigned hi = (unsigned)o4[2] | ((unsigned)o4[3] << 16);
    uint2 u; u.x = lo; u.y = hi;
    *(uint2*)(dst + (size_t)tr * N_ + tc + i * 4) = u;
  }
}

// ---------------- compact flash attention: 16-q strips, 4 waves split keys, LDS merge ----------------
__global__ __launch_bounds__(256) void k_attn(
    const unsigned short* __restrict__ qc, const unsigned short* __restrict__ kc,
    const unsigned short* __restrict__ vctr, unsigned short* __restrict__ vnew,
    const unsigned int* __restrict__ idx, const unsigned int* __restrict__ cnt) {
  __shared__ __align__(16) unsigned short p_lds[4][16 * 72];
  __shared__ float macc[4][16][65];
  __shared__ float mml[4][2][16];
  int qt = blockIdx.x, h = blockIdx.y, b = blockIdx.z;
  int nq = (int)cnt[b], nk = (int)cnt[B_ + b];
  int q0 = qt * 16;
  if (q0 >= nq) return;                                  // uniform exit
  int t = threadIdx.x, wave = t >> 6, lane = t & 63;
  const unsigned short* qp =
      qc + ((size_t)b * N_ + q0 + (lane & 15)) * C_ + h * HD_ + ((lane >> 4) * 8);
  bf16x8 qf0 = *(const bf16x8*)qp;
  bf16x8 qf1 = *(const bf16x8*)(qp + 32);
  float mrow[4], lrow[4];
  f32x4 acc[4];
#pragma unroll
  for (int r = 0; r < 4; r++) { mrow[r] = -1e30f; lrow[r] = 0.f; }
#pragma unroll
  for (int d = 0; d < 4; d++) acc[d] = f32x4{0.f, 0.f, 0.f, 0.f};
  // wave-private key chunks: no barriers, no K/V LDS — direct global->VGPR (L2-hot)
  for (int j0 = wave * 64; j0 < nk; j0 += 256) {
    f32x4 s[4];
#pragma unroll
    for (int nf = 0; nf < 4; nf++) {
      const unsigned short* kp =
          kc + ((size_t)b * N_ + j0 + nf * 16 + (lane & 15)) * C_ + h * HD_ + ((lane >> 4) * 8);
      bf16x8 kf0 = *(const bf16x8*)kp;
      bf16x8 kf1 = *(const bf16x8*)(kp + 32);
      f32x4 z = {0.f, 0.f, 0.f, 0.f};
      z = __builtin_amdgcn_mfma_f32_16x16x32_bf16(qf0, kf0, z, 0, 0, 0);
      z = __builtin_amdgcn_mfma_f32_16x16x32_bf16(qf1, kf1, z, 0, 0, 0);
      float mv = ((j0 + nf * 16 + (lane & 15)) < nk) ? 0.f : -1e30f;
#pragma unroll
      for (int r = 0; r < 4; r++) s[nf][r] = z[r] * 0.125f + mv;
    }
    float alpha[4];
#pragma unroll
    for (int r = 0; r < 4; r++) {
      float mx = fmaxf(fmaxf(s[0][r], s[1][r]), fmaxf(s[2][r], s[3][r]));
      mx = fmaxf(mx, __shfl_xor(mx, 1));
      mx = fmaxf(mx, __shfl_xor(mx, 2));
      mx = fmaxf(mx, __shfl_xor(mx, 4));
      mx = fmaxf(mx, __shfl_xor(mx, 8));
      float mn = fmaxf(mrow[r], mx);
      alpha[r] = __expf(mrow[r] - mn);
      mrow[r] = mn;
      float rs = 0.f;
      int ql = ((lane >> 4) << 2) + r;
#pragma unroll
      for (int nf = 0; nf < 4; nf++) {
        float sv = s[nf][r];
        float p = (sv < -1e29f) ? 0.f : __expf(sv - mn);
        rs += p;
        p_lds[wave][ql * 72 + nf * 16 + (lane & 15)] = f2bf(p);
      }
      rs += __shfl_xor(rs, 1);
      rs += __shfl_xor(rs, 2);
      rs += __shfl_xor(rs, 4);
      rs += __shfl_xor(rs, 8);
      lrow[r] = lrow[r] * alpha[r] + rs;
    }
    bf16x8 pa0 = *(const bf16x8*)&p_lds[wave][(lane & 15) * 72 + ((lane >> 4) * 8)];
    bf16x8 pa1 = *(const bf16x8*)&p_lds[wave][(lane & 15) * 72 + 32 + ((lane >> 4) * 8)];
#pragma unroll
    for (int df = 0; df < 4; df++) {
#pragma unroll
      for (int r = 0; r < 4; r++) acc[df][r] *= alpha[r];
      const unsigned short* vp =
          vctr + ((size_t)b * C_ + h * HD_ + df * 16 + (lane & 15)) * N_ + j0 + ((lane >> 4) * 8);
      bf16x8 vf0 = *(const bf16x8*)vp;
      bf16x8 vf1 = *(const bf16x8*)(vp + 32);
      acc[df] = __builtin_amdgcn_mfma_f32_16x16x32_bf16(pa0, vf0, acc[df], 0, 0, 0);
      acc[df] = __builtin_amdgcn_mfma_f32_16x16x32_bf16(pa1, vf1, acc[df], 0, 0, 0);
    }
  }
  // deposit per-wave partial state
#pragma unroll
  for (int df = 0; df < 4; df++)
#pragma unroll
    for (int r = 0; r < 4; r++)
      macc[wave][((lane >> 4) << 2) + r][df * 16 + (lane & 15)] = acc[df][r];
  if ((lane & 15) == 0) {
#pragma unroll
    for (int r = 0; r < 4; r++) {
      mml[wave][0][((lane >> 4) << 2) + r] = mrow[r];
      mml[wave][1][((lane >> 4) << 2) + r] = lrow[r];
    }
  }
  __syncthreads();
  // merge 4 wave-partials: thread t -> q = t>>4, d0 = (t&15)*4
  {
    int q = t >> 4, d0 = (t & 15) * 4;
    float mg = fmaxf(fmaxf(mml[0][0][q], mml[1][0][q]), fmaxf(mml[2][0][q], mml[3][0][q]));
    float lg = 0.f, o0 = 0.f, o1 = 0.f, o2 = 0.f, o3 = 0.f;
#pragma unroll
    for (int w = 0; w < 4; w++) {
      float sc = __expf(mml[w][0][q] - mg);
      lg += mml[w][1][q] * sc;
      o0 += macc[w][q][d0 + 0] * sc;
      o1 += macc[w][q][d0 + 1] * sc;
      o2 += macc[w][q][d0 + 2] * sc;
      o3 += macc[w][q][d0 + 3] * sc;
    }
    if (q0 + q < nq) {
      unsigned int qrow = idx[(size_t)b * N_ + q0 + q];
      float inv = 1.0f / lg;
      unsigned short o4[4] = {f2bf(o0 * inv), f2bf(o1 * inv), f2bf(o2 * inv), f2bf(o3 * inv)};
      unsigned lo = (unsigned)o4[0] | ((unsigned)o4[1] << 16);
      unsigned hi = (unsigned)o4[2] | ((unsigned)o4[3] << 16);
      uint2 u; u.x = lo; u.y = hi;
      *(uint2*)(vnew + ((size_t)b * N_ + qrow) * C_ + h * HD_ + d0) = u;
    }
  }
}

extern "C" void kernel_launch(void* const* d_in, const int* in_sizes, int n_in,
                              void* d_out, int out_size, void* d_ws, size_t ws_size,
                              hipStream_t stream) {
  const float* x   = (const float*)d_in[0];
  const float* u_q = (const float*)d_in[1];
  const float* u_k = (const float*)d_in[2];
  const float* wqs = (const float*)d_in[3];
  const float* bqs = (const float*)d_in[4];
  const float* wks = (const float*)d_in[5];
  const float* bks = (const float*)d_in[6];
  const float* Wq  = (const float*)d_in[7];
  const float* bq  = (const float*)d_in[8];
  const float* Wk  = (const float*)d_in[9];
  const float* bk  = (const float*)d_in[10];
  const float* Wv  = (const float*)d_in[11];
  const float* bv  = (const float*)d_in[12];
  const float* Wp  = (const float*)d_in[13];
  const float* bp  = (const float*)d_in[14];

  char* ws = (char*)d_ws;
  unsigned short* xT   = (unsigned short*)(ws);              // 8 MB
  unsigned short* wbf  = (unsigned short*)(ws + 8388608);    // 2 MB
  unsigned short* qkv  = (unsigned short*)(ws + 10485760);   // 3 x 8 MB (qc, kc, vT)
  unsigned short* qc   = qkv;
  unsigned short* kc   = qkv + (size_t)B_ * N_ * C_;
  unsigned short* vT   = kc + (size_t)B_ * N_ * C_;          // dense v; v_new in-place
  unsigned short* vctr = (unsigned short*)(ws + 35651584);   // 8 MB
  unsigned int*   sel  = (unsigned int*)(ws + 44040192);     // 64 KB [2][B][N]
  unsigned int*   idx  = (unsigned int*)(ws + 44105728);     // 64 KB [2][B][N]
  unsigned int*   cnt  = (unsigned int*)(ws + 44171264);     // 64 B  [2][B]

  k_prep<<<dim3(2304), 256, 0, stream>>>(x, u_q, u_k, wqs, bqs, wks, bks,
                                         Wq, Wk, Wv, Wp, xT, wbf, sel);
  k_scan<<<dim3(2, 8), 1024, 0, stream>>>(sel, idx, cnt);
  k_gemm<0><<<dim3(16, 4, 24), 256, 0, stream>>>(wbf, xT, bq, bk, bv, idx, cnt, (void*)qkv);
  k_gather_vt<<<dim3(16, 8, 8), 256, 0, stream>>>(vT, idx, cnt, vctr);
  k_attn<<<dim3(64, 8, 8), 256, 0, stream>>>(qc, kc, vctr, vT, idx, cnt);
  k_gemm<1><<<dim3(16, 4, 8), 256, 0, stream>>>(wbf + 3 * 262144, vT, bp, bp, bp, idx, cnt, d_out);
}